// Round 4
// baseline (630.364 us; speedup 1.0000x reference)
//
#include <hip/hip_runtime.h>

#define B_ 4
#define N_ 2048
#define M_ 2048
#define M2_ 4096
#define D_ 128
#define K_ 512

__constant__ float LIGQ[10]  = {0.f,-0.3f,-0.4f,-0.1f,0.1f,-0.2f,-0.1f,-0.1f,-0.1f,0.1f};
__constant__ float PROTQ[4]  = {0.f,-0.3f,-0.4f,-0.2f};

// accumulator slots (doubles at ws+0)
#define A_TCR  0   // sum (d_yp - Tc)^2
#define A_ELEC 1   // sum qq/dd
#define A_VDW  2   // sum dd^-12 - dd^-6
#define A_TYY  3   // sum (d_yy - Ts)^2
#define A_VQ   4   // sum (z_q - enc)^2

// ---------------------------------------------------------------- init
__global__ __launch_bounds__(256) void k_init(unsigned* rowmin, unsigned* colmin,
                                              unsigned long long* vqbest, double* acc) {
    int i = blockIdx.x * 256 + threadIdx.x;
    if (i < 8) acc[i] = 0.0;
    if (i < B_ * N_) rowmin[i] = 0x7F800000u;          // +inf bits
    if (i < B_ * M_) colmin[i] = 0x7F800000u;
    if (i < B_ * M_) vqbest[i] = 0xFFFFFFFFFFFFFFFFULL;
}

// ---------------------------------------------------------------- prep: e2, charges
__global__ __launch_bounds__(256) void k_prep(const float* __restrict__ emb,
                                              const float* __restrict__ sf,
                                              const float* __restrict__ pf,
                                              float* e2, float* lq, float* pq) {
    int i = blockIdx.x * 256 + threadIdx.x;
    if (i < K_) {
        const float* e = emb + (size_t)i * D_;
        float s0 = 0.f, s1 = 0.f, s2 = 0.f, s3 = 0.f;
        for (int d = 0; d < D_; d += 4) {
            s0 = fmaf(e[d+0], e[d+0], s0);
            s1 = fmaf(e[d+1], e[d+1], s1);
            s2 = fmaf(e[d+2], e[d+2], s2);
            s3 = fmaf(e[d+3], e[d+3], s3);
        }
        e2[i] = (s0 + s1) + (s2 + s3);
    }
    int j = i - K_;
    if (j >= 0 && j < B_ * M_) {
        const float* f = sf + (size_t)j * D_;
        float best = f[0]; int bi = 0;
        for (int k = 1; k < 10; k++) { float v = f[k]; if (v > best) { best = v; bi = k; } }
        lq[j] = LIGQ[bi];
    }
    int p = i - K_ - B_ * M_;
    if (p >= 0 && p < B_ * M2_) {
        const float* f = pf + (size_t)p * D_;
        float best = f[0]; int bi = 0;
        for (int k = 1; k < 4; k++) { float v = f[k]; if (v > best) { best = v; bi = k; } }
        pq[p] = PROTQ[bi];
    }
}

// ---------------------------------------------------------------- VQ argmin GEMM
// tiles: 128 rows x 128 codes, 256 threads, thread = 8x8, K staged in 2 halves of 64
__global__ __launch_bounds__(256) void k_vq(const float* __restrict__ enc,
                                            const float* __restrict__ emb,
                                            const float* __restrict__ e2g,
                                            unsigned long long* best) {
    __shared__ __align__(16) float lf[128 * 64];
    __shared__ __align__(16) float le[128 * 64];
    int bid = blockIdx.x;
    int rt = bid >> 2, ct = bid & 3;
    int r0 = rt * 128, c0 = ct * 128;
    int tid = threadIdx.x;
    int tj = tid & 15, ti = tid >> 4;

    float acc[8][8];
#pragma unroll
    for (int a = 0; a < 8; a++)
#pragma unroll
        for (int b = 0; b < 8; b++) acc[a][b] = 0.f;

    for (int kc = 0; kc < 2; kc++) {
        // stage 128x64 of each, XOR-swizzled per 8-row group
        for (int v = tid; v < 128 * 16; v += 256) {
            int r  = v >> 4;
            int d4 = (v & 15) << 2;
            int dsw = d4 ^ (((r >> 3) & 7) << 2);
            *(float4*)&lf[r * 64 + dsw] = *(const float4*)&enc[((size_t)(r0 + r)) * D_ + kc * 64 + d4];
            *(float4*)&le[r * 64 + dsw] = *(const float4*)&emb[((size_t)(c0 + r)) * D_ + kc * 64 + d4];
        }
        __syncthreads();
#pragma unroll 4
        for (int d4 = 0; d4 < 64; d4 += 4) {
            float4 fa[8], eb[8];
            int fsw = d4 ^ ((ti & 7) << 2);
            int esw = d4 ^ ((tj & 7) << 2);
#pragma unroll
            for (int rr = 0; rr < 8; rr++) fa[rr] = *(float4*)&lf[(ti * 8 + rr) * 64 + fsw];
#pragma unroll
            for (int cc = 0; cc < 8; cc++) eb[cc] = *(float4*)&le[(tj * 8 + cc) * 64 + esw];
#pragma unroll
            for (int rr = 0; rr < 8; rr++)
#pragma unroll
                for (int cc = 0; cc < 8; cc++) {
                    acc[rr][cc] = fmaf(fa[rr].x, eb[cc].x, acc[rr][cc]);
                    acc[rr][cc] = fmaf(fa[rr].y, eb[cc].y, acc[rr][cc]);
                    acc[rr][cc] = fmaf(fa[rr].z, eb[cc].z, acc[rr][cc]);
                    acc[rr][cc] = fmaf(fa[rr].w, eb[cc].w, acc[rr][cc]);
                }
        }
        __syncthreads();
    }

    // per-row best over this block's 128 codes; pack (orderable score | idx)
    unsigned long long* red = (unsigned long long*)lf;   // reuse, 128*17*8 B < 32 KB
#pragma unroll
    for (int rr = 0; rr < 8; rr++) {
        int r = ti * 8 + rr;
        float bs = __uint_as_float(0x7F800000u); int bidx = 0;
#pragma unroll
        for (int cc = 0; cc < 8; cc++) {
            int c = tj * 8 + cc;
            float s = e2g[c0 + c] - 2.f * acc[rr][cc];
            if (s < bs) { bs = s; bidx = c0 + c; }
        }
        unsigned ub = __float_as_uint(bs);
        ub = (ub & 0x80000000u) ? ~ub : (ub | 0x80000000u);
        red[r * 17 + tj] = ((unsigned long long)ub << 32) | (unsigned)bidx;
    }
    __syncthreads();
    if (tid < 128) {
        unsigned long long mn = red[tid * 17 + 0];
        for (int t = 1; t < 16; t++) {
            unsigned long long v = red[tid * 17 + t];
            mn = (v < mn) ? v : mn;
        }
        atomicMin(&best[r0 + tid], mn);
    }
}

// ---------------------------------------------------------------- VQ epilogue: MSE
__global__ __launch_bounds__(256) void k_vqep(const float* __restrict__ enc,
                                              const float* __restrict__ emb,
                                              const unsigned long long* __restrict__ best,
                                              double* acc) {
    int w = (blockIdx.x * 256 + threadIdx.x) >> 6;
    int lane = threadIdx.x & 63;
    if (w >= B_ * M_) return;
    int idx = (int)(best[w] & 0xFFFFFFFFu);
    float2 fv = *(const float2*)&enc[(size_t)w * D_ + lane * 2];
    float2 ev = *(const float2*)&emb[(size_t)idx * D_ + lane * 2];
    float d0 = ev.x - fv.x, d1 = ev.y - fv.y;
    double s = (double)(d0 * d0) + (double)(d1 * d1);
    for (int off = 32; off; off >>= 1) s += __shfl_down(s, off);
    if (lane == 0) atomicAdd(&acc[A_VQ], s);
}

// ---------------------------------------------------------------- cross: tpl_cross + elec + vdw
__global__ __launch_bounds__(256) void k_cross(const float* __restrict__ yg,
                                               const float* __restrict__ pg,
                                               const float* __restrict__ Tc,
                                               const float* __restrict__ lq,
                                               const float* __restrict__ pq,
                                               double* acc) {
    __shared__ float ly[B_ * 64 * 3];
    __shared__ float lp[B_ * 64 * 3];
    __shared__ float llq[B_ * 64];
    __shared__ float lpq[B_ * 64];
    int bid = blockIdx.x;
    int it = bid >> 6, jt = bid & 63;
    int i0 = it * 64, j0 = jt * 64;
    int tid = threadIdx.x;

    for (int t = tid; t < B_ * 192; t += 256) {
        int b = t / 192, r = t % 192;
        ly[t] = yg[((size_t)(b * M_ + i0)) * 3 + r];
        lp[t] = pg[((size_t)(b * M2_ + j0)) * 3 + r];
    }
    for (int t = tid; t < B_ * 64; t += 256) {
        int b = t >> 6, r = t & 63;
        llq[t] = lq[b * M_ + i0 + r];
        lpq[t] = pq[b * M2_ + j0 + r];
    }
    __syncthreads();

    int tj = tid & 15, ti = tid >> 4;
    float tcs[4][4];
#pragma unroll
    for (int a = 0; a < 4; a++) {
        float4 t = *(const float4*)&Tc[((size_t)(i0 + ti * 4 + a)) * M2_ + j0 + tj * 4];
        tcs[a][0] = t.x; tcs[a][1] = t.y; tcs[a][2] = t.z; tcs[a][3] = t.w;
    }

    float s_tpl = 0.f, s_elec = 0.f, s_vdw = 0.f;
#pragma unroll
    for (int b = 0; b < B_; b++) {
        float ax[4], ay[4], az[4], aq[4];
#pragma unroll
        for (int a = 0; a < 4; a++) {
            int r = ti * 4 + a;
            ax[a] = ly[(b * 64 + r) * 3 + 0];
            ay[a] = ly[(b * 64 + r) * 3 + 1];
            az[a] = ly[(b * 64 + r) * 3 + 2];
            aq[a] = llq[b * 64 + r];
        }
#pragma unroll
        for (int jj = 0; jj < 4; jj++) {
            int c = tj * 4 + jj;
            float px = lp[(b * 64 + c) * 3 + 0];
            float py = lp[(b * 64 + c) * 3 + 1];
            float pz = lp[(b * 64 + c) * 3 + 2];
            float qc = lpq[b * 64 + c];
#pragma unroll
            for (int a = 0; a < 4; a++) {
                float dx = ax[a] - px, dy = ay[a] - py, dz = az[a] - pz;
                float d2 = fmaf(dz, dz, fmaf(dy, dy, dx * dx));
                float r  = __builtin_amdgcn_sqrtf(d2);
                float s  = r - tcs[a][jj];
                s_tpl = fmaf(s, s, s_tpl);
                float dd  = r + 0.01f;
                float inv = __builtin_amdgcn_rcpf(dd);
                float i2 = inv * inv;
                float i6 = i2 * i2 * i2;
                float i12 = i6 * i6;
                s_vdw += i12 - i6;
                s_elec = fmaf(aq[a] * qc, inv, s_elec);
            }
        }
    }
    double dt = (double)s_tpl, de = (double)s_elec, dv = (double)s_vdw;
    for (int off = 32; off; off >>= 1) {
        dt += __shfl_down(dt, off);
        de += __shfl_down(de, off);
        dv += __shfl_down(dv, off);
    }
    if ((tid & 63) == 0) {
        atomicAdd(&acc[A_TCR], dt);
        atomicAdd(&acc[A_ELEC], de);
        atomicAdd(&acc[A_VDW], dv);
    }
}

// ---------------------------------------------------------------- yy: tpl_scaffold
__global__ __launch_bounds__(256) void k_yy(const float* __restrict__ yg,
                                            const float* __restrict__ Ts,
                                            double* acc) {
    __shared__ float la[B_ * 64 * 3];
    __shared__ float lb[B_ * 64 * 3];
    int bid = blockIdx.x;
    int it = bid >> 5, jt = bid & 31;
    int i0 = it * 64, j0 = jt * 64;
    int tid = threadIdx.x;

    for (int t = tid; t < B_ * 192; t += 256) {
        int b = t / 192, r = t % 192;
        la[t] = yg[((size_t)(b * M_ + i0)) * 3 + r];
        lb[t] = yg[((size_t)(b * M_ + j0)) * 3 + r];
    }
    __syncthreads();

    int tj = tid & 15, ti = tid >> 4;
    float tcs[4][4];
#pragma unroll
    for (int a = 0; a < 4; a++) {
        float4 t = *(const float4*)&Ts[((size_t)(i0 + ti * 4 + a)) * M_ + j0 + tj * 4];
        tcs[a][0] = t.x; tcs[a][1] = t.y; tcs[a][2] = t.z; tcs[a][3] = t.w;
    }
    float s_tpl = 0.f;
#pragma unroll
    for (int b = 0; b < B_; b++) {
        float ax[4], ay[4], az[4];
#pragma unroll
        for (int a = 0; a < 4; a++) {
            int r = ti * 4 + a;
            ax[a] = la[(b * 64 + r) * 3 + 0];
            ay[a] = la[(b * 64 + r) * 3 + 1];
            az[a] = la[(b * 64 + r) * 3 + 2];
        }
#pragma unroll
        for (int jj = 0; jj < 4; jj++) {
            int c = tj * 4 + jj;
            float px = lb[(b * 64 + c) * 3 + 0];
            float py = lb[(b * 64 + c) * 3 + 1];
            float pz = lb[(b * 64 + c) * 3 + 2];
#pragma unroll
            for (int a = 0; a < 4; a++) {
                float dx = ax[a] - px, dy = ay[a] - py, dz = az[a] - pz;
                float d2 = fmaf(dz, dz, fmaf(dy, dy, dx * dx));
                float r  = __builtin_amdgcn_sqrtf(d2);
                float s  = r - tcs[a][jj];
                s_tpl = fmaf(s, s, s_tpl);
            }
        }
    }
    double dt = (double)s_tpl;
    for (int off = 32; off; off >>= 1) dt += __shfl_down(dt, off);
    if ((tid & 63) == 0) atomicAdd(&acc[A_TYY], dt);
}

// ---------------------------------------------------------------- chamfer one side
// rows A (B x 2048 x 3) vs cols Bsd (B x 2048 x 3); min d^2 per row via atomicMin on bits
__global__ __launch_bounds__(256) void k_chamfer(const float* __restrict__ A,
                                                 const float* __restrict__ Bsd,
                                                 unsigned* outmin) {
    __shared__ float4 lb[128];
    int bid = blockIdx.x;
    int rb = bid >> 4;          // 0..7  (1024 rows each)
    int jc = bid & 15;          // 0..15 (128 cols each)
    int b  = rb >> 1;
    int lr0 = (rb & 1) * 1024 + threadIdx.x * 4;
    int j0 = jc * 128;

    for (int t = threadIdx.x; t < 128 * 3; t += 256) {
        int j = t / 3, c = t % 3;
        ((float*)&lb[j])[c] = Bsd[((size_t)(b * 2048 + j0 + j)) * 3 + c];
    }
    __syncthreads();

    float ax[4], ay[4], az[4], m2[4];
#pragma unroll
    for (int a = 0; a < 4; a++) {
        const float* p = &A[((size_t)(b * 2048 + lr0 + a)) * 3];
        ax[a] = p[0]; ay[a] = p[1]; az[a] = p[2];
        m2[a] = __uint_as_float(0x7F800000u);
    }
    for (int j = 0; j < 128; j++) {
        float4 pv = lb[j];
#pragma unroll
        for (int a = 0; a < 4; a++) {
            float dx = ax[a] - pv.x, dy = ay[a] - pv.y, dz = az[a] - pv.z;
            float d2 = fmaf(dz, dz, fmaf(dy, dy, dx * dx));
            m2[a] = fminf(m2[a], d2);
        }
    }
#pragma unroll
    for (int a = 0; a < 4; a++)
        atomicMin(&outmin[b * 2048 + lr0 + a], __float_as_uint(m2[a]));
}

// ---------------------------------------------------------------- final combine
__global__ __launch_bounds__(256) void k_final(const unsigned* __restrict__ rowmin,
                                               const unsigned* __restrict__ colmin,
                                               const double* __restrict__ acc,
                                               float* out) {
    __shared__ double sh[256];
    int tid = threadIdx.x;
    double s = 0.0;
    for (int i = tid; i < B_ * N_; i += 256) s += (double)__builtin_amdgcn_sqrtf(__uint_as_float(rowmin[i]));
    for (int i = tid; i < B_ * M_; i += 256) s += (double)__builtin_amdgcn_sqrtf(__uint_as_float(colmin[i]));
    sh[tid] = s;
    __syncthreads();
    for (int st = 128; st; st >>= 1) { if (tid < st) sh[tid] += sh[tid + st]; __syncthreads(); }
    if (tid == 0) {
        double chamfer = sh[0] / (double)(B_ * N_);                       // N_ == M_
        double vq  = 1.25 * acc[A_VQ] / (double)((size_t)B_ * M_ * D_);
        double tyy = acc[A_TYY] / (double)((size_t)B_ * M_ * M_);
        double tcr = acc[A_TCR] / (double)((size_t)B_ * M_ * M2_);
        double el  = 0.1 * (acc[A_ELEC] + acc[A_VDW]) / (double)B_;
        out[0] = (float)(chamfer + vq + tyy + tcr + el);
    }
}

// ---------------------------------------------------------------- launch
extern "C" void kernel_launch(void* const* d_in, const int* in_sizes, int n_in,
                              void* d_out, int out_size, void* d_ws, size_t ws_size,
                              hipStream_t stream) {
    const float* x   = (const float*)d_in[0];
    const float* y   = (const float*)d_in[1];
    const float* enc = (const float*)d_in[2];
    const float* pc  = (const float*)d_in[3];
    const float* sf  = (const float*)d_in[4];
    const float* pf  = (const float*)d_in[5];
    const float* Ts  = (const float*)d_in[6];
    const float* Tc  = (const float*)d_in[7];
    const float* emb = (const float*)d_in[8];
    float* out = (float*)d_out;

    char* ws = (char*)d_ws;
    double* acc              = (double*)(ws + 0);        // 8 doubles
    unsigned* rowmin         = (unsigned*)(ws + 64);     // 8192 u32
    unsigned* colmin         = (unsigned*)(ws + 32832);  // 8192 u32
    float* lq                = (float*)(ws + 65600);     // 8192 f32
    float* pq                = (float*)(ws + 98368);     // 16384 f32
    float* e2                = (float*)(ws + 163904);    // 512 f32
    unsigned long long* vqb  = (unsigned long long*)(ws + 165952); // 8192 u64

    hipLaunchKernelGGL(k_init, dim3(32), dim3(256), 0, stream, rowmin, colmin, vqb, acc);
    hipLaunchKernelGGL(k_prep, dim3(98), dim3(256), 0, stream, emb, sf, pf, e2, lq, pq);
    hipLaunchKernelGGL(k_vq, dim3(256), dim3(256), 0, stream, enc, emb, e2, vqb);
    hipLaunchKernelGGL(k_vqep, dim3(2048), dim3(256), 0, stream, enc, emb, vqb, acc);
    hipLaunchKernelGGL(k_cross, dim3(2048), dim3(256), 0, stream, y, pc, Tc, lq, pq, acc);
    hipLaunchKernelGGL(k_yy, dim3(1024), dim3(256), 0, stream, y, Ts, acc);
    hipLaunchKernelGGL(k_chamfer, dim3(128), dim3(256), 0, stream, x, y, rowmin);
    hipLaunchKernelGGL(k_chamfer, dim3(128), dim3(256), 0, stream, y, x, colmin);
    hipLaunchKernelGGL(k_final, dim3(1), dim3(256), 0, stream, rowmin, colmin, acc, out);
}

// Round 5
// 628.624 us; speedup vs baseline: 1.0028x; 1.0028x over previous
//
#include <hip/hip_runtime.h>

#define B_ 4
#define N_ 2048
#define M_ 2048
#define M2_ 4096
#define D_ 128
#define K_ 512

__constant__ float LIGQ[10]  = {0.f,-0.3f,-0.4f,-0.1f,0.1f,-0.2f,-0.1f,-0.1f,-0.1f,0.1f};
__constant__ float PROTQ[4]  = {0.f,-0.3f,-0.4f,-0.2f};

// accumulator slots (doubles at ws+0)
#define A_TCR  0
#define A_ELEC 1
#define A_VDW  2
#define A_TYY  3
#define A_VQ   4

// ---------------------------------------------------------------- init
__global__ __launch_bounds__(256) void k_init(unsigned* rowmin, unsigned* colmin,
                                              unsigned long long* vqbest, double* acc) {
    int i = blockIdx.x * 256 + threadIdx.x;
    if (i < 8) acc[i] = 0.0;
    if (i < B_ * N_) rowmin[i] = 0x7F800000u;
    if (i < B_ * M_) colmin[i] = 0x7F800000u;
    if (i < B_ * M_) vqbest[i] = 0xFFFFFFFFFFFFFFFFULL;
}

// ---------------------------------------------------------------- prep: e2, charges
__global__ __launch_bounds__(256) void k_prep(const float* __restrict__ emb,
                                              const float* __restrict__ sf,
                                              const float* __restrict__ pf,
                                              float* e2, float* lq, float* pq) {
    int i = blockIdx.x * 256 + threadIdx.x;
    if (i < K_) {
        const float* e = emb + (size_t)i * D_;
        float s0 = 0.f, s1 = 0.f, s2 = 0.f, s3 = 0.f;
        for (int d = 0; d < D_; d += 4) {
            s0 = fmaf(e[d+0], e[d+0], s0);
            s1 = fmaf(e[d+1], e[d+1], s1);
            s2 = fmaf(e[d+2], e[d+2], s2);
            s3 = fmaf(e[d+3], e[d+3], s3);
        }
        e2[i] = (s0 + s1) + (s2 + s3);
    }
    int j = i - K_;
    if (j >= 0 && j < B_ * M_) {
        const float* f = sf + (size_t)j * D_;
        float best = f[0]; int bi = 0;
        for (int k = 1; k < 10; k++) { float v = f[k]; if (v > best) { best = v; bi = k; } }
        lq[j] = LIGQ[bi];
    }
    int p = i - K_ - B_ * M_;
    if (p >= 0 && p < B_ * M2_) {
        const float* f = pf + (size_t)p * D_;
        float best = f[0]; int bi = 0;
        for (int k = 1; k < 4; k++) { float v = f[k]; if (v > best) { best = v; bi = k; } }
        pq[p] = PROTQ[bi];
    }
}

// ---------------------------------------------------------------- VQ argmin GEMM
__global__ __launch_bounds__(256) void k_vq(const float* __restrict__ enc,
                                            const float* __restrict__ emb,
                                            const float* __restrict__ e2g,
                                            unsigned long long* best) {
    __shared__ __align__(16) float lf[128 * 64];
    __shared__ __align__(16) float le[128 * 64];
    int bid = blockIdx.x;
    int rt = bid >> 2, ct = bid & 3;
    int r0 = rt * 128, c0 = ct * 128;
    int tid = threadIdx.x;
    int tj = tid & 15, ti = tid >> 4;

    float acc[8][8];
#pragma unroll
    for (int a = 0; a < 8; a++)
#pragma unroll
        for (int b = 0; b < 8; b++) acc[a][b] = 0.f;

    for (int kc = 0; kc < 2; kc++) {
        for (int v = tid; v < 128 * 16; v += 256) {
            int r  = v >> 4;
            int d4 = (v & 15) << 2;
            int dsw = d4 ^ (((r >> 3) & 7) << 2);
            *(float4*)&lf[r * 64 + dsw] = *(const float4*)&enc[((size_t)(r0 + r)) * D_ + kc * 64 + d4];
            *(float4*)&le[r * 64 + dsw] = *(const float4*)&emb[((size_t)(c0 + r)) * D_ + kc * 64 + d4];
        }
        __syncthreads();
#pragma unroll 4
        for (int d4 = 0; d4 < 64; d4 += 4) {
            float4 fa[8], eb[8];
            int fsw = d4 ^ ((ti & 7) << 2);
            int esw = d4 ^ ((tj & 7) << 2);
#pragma unroll
            for (int rr = 0; rr < 8; rr++) fa[rr] = *(float4*)&lf[(ti * 8 + rr) * 64 + fsw];
#pragma unroll
            for (int cc = 0; cc < 8; cc++) eb[cc] = *(float4*)&le[(tj * 8 + cc) * 64 + esw];
#pragma unroll
            for (int rr = 0; rr < 8; rr++)
#pragma unroll
                for (int cc = 0; cc < 8; cc++) {
                    acc[rr][cc] = fmaf(fa[rr].x, eb[cc].x, acc[rr][cc]);
                    acc[rr][cc] = fmaf(fa[rr].y, eb[cc].y, acc[rr][cc]);
                    acc[rr][cc] = fmaf(fa[rr].z, eb[cc].z, acc[rr][cc]);
                    acc[rr][cc] = fmaf(fa[rr].w, eb[cc].w, acc[rr][cc]);
                }
        }
        __syncthreads();
    }

    unsigned long long* red = (unsigned long long*)lf;
#pragma unroll
    for (int rr = 0; rr < 8; rr++) {
        int r = ti * 8 + rr;
        float bs = __uint_as_float(0x7F800000u); int bidx = 0;
#pragma unroll
        for (int cc = 0; cc < 8; cc++) {
            int c = tj * 8 + cc;
            float s = e2g[c0 + c] - 2.f * acc[rr][cc];
            if (s < bs) { bs = s; bidx = c0 + c; }
        }
        unsigned ub = __float_as_uint(bs);
        ub = (ub & 0x80000000u) ? ~ub : (ub | 0x80000000u);
        red[r * 17 + tj] = ((unsigned long long)ub << 32) | (unsigned)bidx;
    }
    __syncthreads();
    if (tid < 128) {
        unsigned long long mn = red[tid * 17 + 0];
        for (int t = 1; t < 16; t++) {
            unsigned long long v = red[tid * 17 + t];
            mn = (v < mn) ? v : mn;
        }
        atomicMin(&best[r0 + tid], mn);
    }
}

// ---------------------------------------------------------------- VQ epilogue: MSE
__global__ __launch_bounds__(256) void k_vqep(const float* __restrict__ enc,
                                              const float* __restrict__ emb,
                                              const unsigned long long* __restrict__ best,
                                              double* acc) {
    int w = (blockIdx.x * 256 + threadIdx.x) >> 6;
    int lane = threadIdx.x & 63;
    if (w >= B_ * M_) return;
    int idx = (int)(best[w] & 0xFFFFFFFFu);
    float2 fv = *(const float2*)&enc[(size_t)w * D_ + lane * 2];
    float2 ev = *(const float2*)&emb[(size_t)idx * D_ + lane * 2];
    float d0 = ev.x - fv.x, d1 = ev.y - fv.y;
    double s = (double)(d0 * d0) + (double)(d1 * d1);
    for (int off = 32; off; off >>= 1) s += __shfl_down(s, off);
    if (lane == 0) atomicAdd(&acc[A_VQ], s);
}

// ---------------------------------------------------------------- cross: tpl_cross + elec + vdw
// 256 thr = 16(ti rows) x 16(tj cols); thread tile 4x4; cols strided c=jj*16+tj
// operands pre-packed float4(x,y,z,q) in LDS -> ds_read_b128, 2-way banks (free)
__global__ __launch_bounds__(256) void k_cross(const float* __restrict__ yg,
                                               const float* __restrict__ pg,
                                               const float* __restrict__ Tc,
                                               const float* __restrict__ lq,
                                               const float* __restrict__ pq,
                                               double* acc) {
    __shared__ __align__(16) float4 lyq[B_ * 64];
    __shared__ __align__(16) float4 lpq[B_ * 64];
    int bid = blockIdx.x;
    int it = bid >> 6, jt = bid & 63;
    int i0 = it * 64, j0 = jt * 64;
    int tid = threadIdx.x;

    {   // stage: one float4 per thread per side
        int b = tid >> 6, r = tid & 63;
        const float* yp = &yg[((size_t)(b * M_ + i0 + r)) * 3];
        lyq[tid] = make_float4(yp[0], yp[1], yp[2], lq[b * M_ + i0 + r]);
        const float* pp = &pg[((size_t)(b * M2_ + j0 + r)) * 3];
        lpq[tid] = make_float4(pp[0], pp[1], pp[2], pq[b * M2_ + j0 + r]);
    }
    __syncthreads();

    int tj = tid & 15, ti = tid >> 4;
    float tcs[4][4];
#pragma unroll
    for (int a = 0; a < 4; a++) {
        const float* tr = &Tc[((size_t)(i0 + ti * 4 + a)) * M2_ + j0 + tj];
#pragma unroll
        for (int jj = 0; jj < 4; jj++) tcs[a][jj] = tr[jj * 16];
    }

    float s_tpl = 0.f, s_elec = 0.f, s_vdw = 0.f;
#pragma unroll
    for (int b = 0; b < B_; b++) {
        float4 row[4], col[4];
#pragma unroll
        for (int a = 0; a < 4; a++) row[a] = lyq[b * 64 + ti * 4 + a];
#pragma unroll
        for (int jj = 0; jj < 4; jj++) col[jj] = lpq[b * 64 + jj * 16 + tj];
#pragma unroll
        for (int jj = 0; jj < 4; jj++)
#pragma unroll
            for (int a = 0; a < 4; a++) {
                float dx = row[a].x - col[jj].x;
                float dy = row[a].y - col[jj].y;
                float dz = row[a].z - col[jj].z;
                float d2 = fmaf(dz, dz, fmaf(dy, dy, dx * dx));
                float r  = __builtin_amdgcn_sqrtf(d2);
                float s  = r - tcs[a][jj];
                s_tpl = fmaf(s, s, s_tpl);
                float dd  = r + 0.01f;
                float inv = __builtin_amdgcn_rcpf(dd);
                float i2 = inv * inv;
                float i6 = i2 * i2 * i2;
                s_vdw = fmaf(i6, i6 - 1.f, s_vdw);              // i12 - i6
                s_elec = fmaf(row[a].w * col[jj].w, inv, s_elec);
            }
    }
    double dt = (double)s_tpl, de = (double)s_elec, dv = (double)s_vdw;
    for (int off = 32; off; off >>= 1) {
        dt += __shfl_down(dt, off);
        de += __shfl_down(de, off);
        dv += __shfl_down(dv, off);
    }
    if ((tid & 63) == 0) {
        atomicAdd(&acc[A_TCR], dt);
        atomicAdd(&acc[A_ELEC], de);
        atomicAdd(&acc[A_VDW], dv);
    }
}

// ---------------------------------------------------------------- yy: tpl_scaffold
__global__ __launch_bounds__(256) void k_yy(const float* __restrict__ yg,
                                            const float* __restrict__ Ts,
                                            double* acc) {
    __shared__ __align__(16) float4 la4[B_ * 64];
    __shared__ __align__(16) float4 lb4[B_ * 64];
    int bid = blockIdx.x;
    int it = bid >> 5, jt = bid & 31;
    int i0 = it * 64, j0 = jt * 64;
    int tid = threadIdx.x;

    {
        int b = tid >> 6, r = tid & 63;
        const float* ap = &yg[((size_t)(b * M_ + i0 + r)) * 3];
        la4[tid] = make_float4(ap[0], ap[1], ap[2], 0.f);
        const float* bp = &yg[((size_t)(b * M_ + j0 + r)) * 3];
        lb4[tid] = make_float4(bp[0], bp[1], bp[2], 0.f);
    }
    __syncthreads();

    int tj = tid & 15, ti = tid >> 4;
    float tcs[4][4];
#pragma unroll
    for (int a = 0; a < 4; a++) {
        const float* tr = &Ts[((size_t)(i0 + ti * 4 + a)) * M_ + j0 + tj];
#pragma unroll
        for (int jj = 0; jj < 4; jj++) tcs[a][jj] = tr[jj * 16];
    }
    float s_tpl = 0.f;
#pragma unroll
    for (int b = 0; b < B_; b++) {
        float4 row[4], col[4];
#pragma unroll
        for (int a = 0; a < 4; a++) row[a] = la4[b * 64 + ti * 4 + a];
#pragma unroll
        for (int jj = 0; jj < 4; jj++) col[jj] = lb4[b * 64 + jj * 16 + tj];
#pragma unroll
        for (int jj = 0; jj < 4; jj++)
#pragma unroll
            for (int a = 0; a < 4; a++) {
                float dx = row[a].x - col[jj].x;
                float dy = row[a].y - col[jj].y;
                float dz = row[a].z - col[jj].z;
                float d2 = fmaf(dz, dz, fmaf(dy, dy, dx * dx));
                float r  = __builtin_amdgcn_sqrtf(d2);
                float s  = r - tcs[a][jj];
                s_tpl = fmaf(s, s, s_tpl);
            }
    }
    double dt = (double)s_tpl;
    for (int off = 32; off; off >>= 1) dt += __shfl_down(dt, off);
    if ((tid & 63) == 0) atomicAdd(&acc[A_TYY], dt);
}

// ---------------------------------------------------------------- chamfer one side
// grid: 32 row-chunks (256 rows) x 16 col-chunks (128 cols) = 512 blocks
__global__ __launch_bounds__(256) void k_chamfer(const float* __restrict__ A,
                                                 const float* __restrict__ Bsd,
                                                 unsigned* outmin) {
    __shared__ float4 lb[128];
    int bid = blockIdx.x;
    int rc = bid >> 4;
    int jc = bid & 15;
    int row = rc * 256 + threadIdx.x;      // global row over B*2048
    int b = row >> 11;
    int j0 = jc * 128;

    for (int t = threadIdx.x; t < 128 * 3; t += 256) {
        int j = t / 3, c = t % 3;
        ((float*)&lb[j])[c] = Bsd[((size_t)(b * 2048 + j0 + j)) * 3 + c];
    }
    __syncthreads();

    const float* p = &A[(size_t)row * 3];
    float ax = p[0], ay = p[1], az = p[2];
    float m2 = __uint_as_float(0x7F800000u);
#pragma unroll 4
    for (int j = 0; j < 128; j++) {
        float4 pv = lb[j];
        float dx = ax - pv.x, dy = ay - pv.y, dz = az - pv.z;
        m2 = fminf(m2, fmaf(dz, dz, fmaf(dy, dy, dx * dx)));
    }
    atomicMin(&outmin[row], __float_as_uint(m2));
}

// ---------------------------------------------------------------- final combine
__global__ __launch_bounds__(256) void k_final(const unsigned* __restrict__ rowmin,
                                               const unsigned* __restrict__ colmin,
                                               const double* __restrict__ acc,
                                               float* out) {
    __shared__ double sh[256];
    int tid = threadIdx.x;
    double s = 0.0;
    for (int i = tid; i < B_ * N_; i += 256) s += (double)__builtin_amdgcn_sqrtf(__uint_as_float(rowmin[i]));
    for (int i = tid; i < B_ * M_; i += 256) s += (double)__builtin_amdgcn_sqrtf(__uint_as_float(colmin[i]));
    sh[tid] = s;
    __syncthreads();
    for (int st = 128; st; st >>= 1) { if (tid < st) sh[tid] += sh[tid + st]; __syncthreads(); }
    if (tid == 0) {
        double chamfer = sh[0] / (double)(B_ * N_);
        double vq  = 1.25 * acc[A_VQ] / (double)((size_t)B_ * M_ * D_);
        double tyy = acc[A_TYY] / (double)((size_t)B_ * M_ * M_);
        double tcr = acc[A_TCR] / (double)((size_t)B_ * M_ * M2_);
        double el  = 0.1 * (acc[A_ELEC] + acc[A_VDW]) / (double)B_;
        out[0] = (float)(chamfer + vq + tyy + tcr + el);
    }
}

// ---------------------------------------------------------------- launch
extern "C" void kernel_launch(void* const* d_in, const int* in_sizes, int n_in,
                              void* d_out, int out_size, void* d_ws, size_t ws_size,
                              hipStream_t stream) {
    const float* x   = (const float*)d_in[0];
    const float* y   = (const float*)d_in[1];
    const float* enc = (const float*)d_in[2];
    const float* pc  = (const float*)d_in[3];
    const float* sf  = (const float*)d_in[4];
    const float* pf  = (const float*)d_in[5];
    const float* Ts  = (const float*)d_in[6];
    const float* Tc  = (const float*)d_in[7];
    const float* emb = (const float*)d_in[8];
    float* out = (float*)d_out;

    char* ws = (char*)d_ws;
    double* acc              = (double*)(ws + 0);
    unsigned* rowmin         = (unsigned*)(ws + 64);
    unsigned* colmin         = (unsigned*)(ws + 32832);
    float* lq                = (float*)(ws + 65600);
    float* pq                = (float*)(ws + 98368);
    float* e2                = (float*)(ws + 163904);
    unsigned long long* vqb  = (unsigned long long*)(ws + 165952);

    hipLaunchKernelGGL(k_init, dim3(32), dim3(256), 0, stream, rowmin, colmin, vqb, acc);
    hipLaunchKernelGGL(k_prep, dim3(98), dim3(256), 0, stream, emb, sf, pf, e2, lq, pq);
    hipLaunchKernelGGL(k_vq, dim3(256), dim3(256), 0, stream, enc, emb, e2, vqb);
    hipLaunchKernelGGL(k_vqep, dim3(2048), dim3(256), 0, stream, enc, emb, vqb, acc);
    hipLaunchKernelGGL(k_cross, dim3(2048), dim3(256), 0, stream, y, pc, Tc, lq, pq, acc);
    hipLaunchKernelGGL(k_yy, dim3(1024), dim3(256), 0, stream, y, Ts, acc);
    hipLaunchKernelGGL(k_chamfer, dim3(512), dim3(256), 0, stream, x, y, rowmin);
    hipLaunchKernelGGL(k_chamfer, dim3(512), dim3(256), 0, stream, y, x, colmin);
    hipLaunchKernelGGL(k_final, dim3(1), dim3(256), 0, stream, rowmin, colmin, acc, out);
}

// Round 6
// 207.340 us; speedup vs baseline: 3.0402x; 3.0319x over previous
//
#include <hip/hip_runtime.h>

#define B_ 4
#define N_ 2048
#define M_ 2048
#define M2_ 4096
#define D_ 128
#define K_ 512

__constant__ float LIGQ[10]  = {0.f,-0.3f,-0.4f,-0.1f,0.1f,-0.2f,-0.1f,-0.1f,-0.1f,0.1f};
__constant__ float PROTQ[4]  = {0.f,-0.3f,-0.4f,-0.2f};

// ---------------------------------------------------------------- init
__global__ __launch_bounds__(256) void k_init(unsigned* rowmin, unsigned* colmin,
                                              unsigned long long* vqbest) {
    int i = blockIdx.x * 256 + threadIdx.x;
    if (i < B_ * N_) rowmin[i] = 0x7F800000u;
    if (i < B_ * M_) colmin[i] = 0x7F800000u;
    if (i < B_ * M_) vqbest[i] = 0xFFFFFFFFFFFFFFFFULL;
}

// ---------------------------------------------------------------- prep: e2, charges
__global__ __launch_bounds__(256) void k_prep(const float* __restrict__ emb,
                                              const float* __restrict__ sf,
                                              const float* __restrict__ pf,
                                              float* e2, float* lq, float* pq) {
    int i = blockIdx.x * 256 + threadIdx.x;
    if (i < K_) {
        const float* e = emb + (size_t)i * D_;
        float s0 = 0.f, s1 = 0.f, s2 = 0.f, s3 = 0.f;
        for (int d = 0; d < D_; d += 4) {
            s0 = fmaf(e[d+0], e[d+0], s0);
            s1 = fmaf(e[d+1], e[d+1], s1);
            s2 = fmaf(e[d+2], e[d+2], s2);
            s3 = fmaf(e[d+3], e[d+3], s3);
        }
        e2[i] = (s0 + s1) + (s2 + s3);
    }
    int j = i - K_;
    if (j >= 0 && j < B_ * M_) {
        const float* f = sf + (size_t)j * D_;
        float best = f[0]; int bi = 0;
        for (int k = 1; k < 10; k++) { float v = f[k]; if (v > best) { best = v; bi = k; } }
        lq[j] = LIGQ[bi];
    }
    int p = i - K_ - B_ * M_;
    if (p >= 0 && p < B_ * M2_) {
        const float* f = pf + (size_t)p * D_;
        float best = f[0]; int bi = 0;
        for (int k = 1; k < 4; k++) { float v = f[k]; if (v > best) { best = v; bi = k; } }
        pq[p] = PROTQ[bi];
    }
}

// ---------------------------------------------------------------- VQ argmin GEMM
__global__ __launch_bounds__(256) void k_vq(const float* __restrict__ enc,
                                            const float* __restrict__ emb,
                                            const float* __restrict__ e2g,
                                            unsigned long long* best) {
    __shared__ __align__(16) float lf[128 * 64];
    __shared__ __align__(16) float le[128 * 64];
    int bid = blockIdx.x;
    int rt = bid >> 2, ct = bid & 3;
    int r0 = rt * 128, c0 = ct * 128;
    int tid = threadIdx.x;
    int tj = tid & 15, ti = tid >> 4;

    float acc[8][8];
#pragma unroll
    for (int a = 0; a < 8; a++)
#pragma unroll
        for (int b = 0; b < 8; b++) acc[a][b] = 0.f;

    for (int kc = 0; kc < 2; kc++) {
        for (int v = tid; v < 128 * 16; v += 256) {
            int r  = v >> 4;
            int d4 = (v & 15) << 2;
            int dsw = d4 ^ (((r >> 3) & 7) << 2);
            *(float4*)&lf[r * 64 + dsw] = *(const float4*)&enc[((size_t)(r0 + r)) * D_ + kc * 64 + d4];
            *(float4*)&le[r * 64 + dsw] = *(const float4*)&emb[((size_t)(c0 + r)) * D_ + kc * 64 + d4];
        }
        __syncthreads();
#pragma unroll 4
        for (int d4 = 0; d4 < 64; d4 += 4) {
            float4 fa[8], eb[8];
            int fsw = d4 ^ ((ti & 7) << 2);
            int esw = d4 ^ ((tj & 7) << 2);
#pragma unroll
            for (int rr = 0; rr < 8; rr++) fa[rr] = *(float4*)&lf[(ti * 8 + rr) * 64 + fsw];
#pragma unroll
            for (int cc = 0; cc < 8; cc++) eb[cc] = *(float4*)&le[(tj * 8 + cc) * 64 + esw];
#pragma unroll
            for (int rr = 0; rr < 8; rr++)
#pragma unroll
                for (int cc = 0; cc < 8; cc++) {
                    acc[rr][cc] = fmaf(fa[rr].x, eb[cc].x, acc[rr][cc]);
                    acc[rr][cc] = fmaf(fa[rr].y, eb[cc].y, acc[rr][cc]);
                    acc[rr][cc] = fmaf(fa[rr].z, eb[cc].z, acc[rr][cc]);
                    acc[rr][cc] = fmaf(fa[rr].w, eb[cc].w, acc[rr][cc]);
                }
        }
        __syncthreads();
    }

    unsigned long long* red = (unsigned long long*)lf;
#pragma unroll
    for (int rr = 0; rr < 8; rr++) {
        int r = ti * 8 + rr;
        float bs = __uint_as_float(0x7F800000u); int bidx = 0;
#pragma unroll
        for (int cc = 0; cc < 8; cc++) {
            int c = tj * 8 + cc;
            float s = e2g[c0 + c] - 2.f * acc[rr][cc];
            if (s < bs) { bs = s; bidx = c0 + c; }
        }
        unsigned ub = __float_as_uint(bs);
        ub = (ub & 0x80000000u) ? ~ub : (ub | 0x80000000u);
        red[r * 17 + tj] = ((unsigned long long)ub << 32) | (unsigned)bidx;
    }
    __syncthreads();
    if (tid < 128) {
        unsigned long long mn = red[tid * 17 + 0];
        for (int t = 1; t < 16; t++) {
            unsigned long long v = red[tid * 17 + t];
            mn = (v < mn) ? v : mn;
        }
        atomicMin(&best[r0 + tid], mn);
    }
}

// ---------------------------------------------------------------- VQ epilogue: MSE -> per-block partial
__global__ __launch_bounds__(256) void k_vqep(const float* __restrict__ enc,
                                              const float* __restrict__ emb,
                                              const unsigned long long* __restrict__ best,
                                              double* pvq) {
    __shared__ double sred[4];
    int tid = threadIdx.x;
    int w = (blockIdx.x * 256 + tid) >> 6;        // global wave = row, always < 8192
    int lane = tid & 63;
    int idx = (int)(best[w] & 0xFFFFFFFFu);
    float2 fv = *(const float2*)&enc[(size_t)w * D_ + lane * 2];
    float2 ev = *(const float2*)&emb[(size_t)idx * D_ + lane * 2];
    float d0 = ev.x - fv.x, d1 = ev.y - fv.y;
    double s = (double)(d0 * d0) + (double)(d1 * d1);
    for (int off = 32; off; off >>= 1) s += __shfl_down(s, off);
    if (lane == 0) sred[tid >> 6] = s;
    __syncthreads();
    if (tid == 0) pvq[blockIdx.x] = (sred[0] + sred[1]) + (sred[2] + sred[3]);
}

// ---------------------------------------------------------------- cross: tpl_cross + elec + vdw
__global__ __launch_bounds__(256) void k_cross(const float* __restrict__ yg,
                                               const float* __restrict__ pg,
                                               const float* __restrict__ Tc,
                                               const float* __restrict__ lq,
                                               const float* __restrict__ pq,
                                               double* pT, double* pE, double* pV) {
    __shared__ __align__(16) float4 lyq[B_ * 64];
    __shared__ __align__(16) float4 lpq[B_ * 64];
    __shared__ double wred[3][4];
    int bid = blockIdx.x;
    int it = bid >> 6, jt = bid & 63;
    int i0 = it * 64, j0 = jt * 64;
    int tid = threadIdx.x;

    {
        int b = tid >> 6, r = tid & 63;
        const float* yp = &yg[((size_t)(b * M_ + i0 + r)) * 3];
        lyq[tid] = make_float4(yp[0], yp[1], yp[2], lq[b * M_ + i0 + r]);
        const float* pp = &pg[((size_t)(b * M2_ + j0 + r)) * 3];
        lpq[tid] = make_float4(pp[0], pp[1], pp[2], pq[b * M2_ + j0 + r]);
    }
    __syncthreads();

    int tj = tid & 15, ti = tid >> 4;
    float tcs[4][4];
#pragma unroll
    for (int a = 0; a < 4; a++) {
        const float* tr = &Tc[((size_t)(i0 + ti * 4 + a)) * M2_ + j0 + tj];
#pragma unroll
        for (int jj = 0; jj < 4; jj++) tcs[a][jj] = tr[jj * 16];
    }

    float s_tpl = 0.f, s_elec = 0.f, s_vdw = 0.f;
#pragma unroll
    for (int b = 0; b < B_; b++) {
        float4 row[4], col[4];
#pragma unroll
        for (int a = 0; a < 4; a++) row[a] = lyq[b * 64 + ti * 4 + a];
#pragma unroll
        for (int jj = 0; jj < 4; jj++) col[jj] = lpq[b * 64 + jj * 16 + tj];
#pragma unroll
        for (int jj = 0; jj < 4; jj++)
#pragma unroll
            for (int a = 0; a < 4; a++) {
                float dx = row[a].x - col[jj].x;
                float dy = row[a].y - col[jj].y;
                float dz = row[a].z - col[jj].z;
                float d2 = fmaf(dz, dz, fmaf(dy, dy, dx * dx));
                float r  = __builtin_amdgcn_sqrtf(d2);
                float s  = r - tcs[a][jj];
                s_tpl = fmaf(s, s, s_tpl);
                float dd  = r + 0.01f;
                float inv = __builtin_amdgcn_rcpf(dd);
                float i2 = inv * inv;
                float i6 = i2 * i2 * i2;
                s_vdw = fmaf(i6, i6 - 1.f, s_vdw);              // i12 - i6
                s_elec = fmaf(row[a].w * col[jj].w, inv, s_elec);
            }
    }
    double dt = (double)s_tpl, de = (double)s_elec, dv = (double)s_vdw;
    for (int off = 32; off; off >>= 1) {
        dt += __shfl_down(dt, off);
        de += __shfl_down(de, off);
        dv += __shfl_down(dv, off);
    }
    int wv = tid >> 6;
    if ((tid & 63) == 0) { wred[0][wv] = dt; wred[1][wv] = de; wred[2][wv] = dv; }
    __syncthreads();
    if (tid == 0) {
        pT[bid] = (wred[0][0] + wred[0][1]) + (wred[0][2] + wred[0][3]);
        pE[bid] = (wred[1][0] + wred[1][1]) + (wred[1][2] + wred[1][3]);
        pV[bid] = (wred[2][0] + wred[2][1]) + (wred[2][2] + wred[2][3]);
    }
}

// ---------------------------------------------------------------- yy: tpl_scaffold
__global__ __launch_bounds__(256) void k_yy(const float* __restrict__ yg,
                                            const float* __restrict__ Ts,
                                            double* pyy) {
    __shared__ __align__(16) float4 la4[B_ * 64];
    __shared__ __align__(16) float4 lb4[B_ * 64];
    __shared__ double wred[4];
    int bid = blockIdx.x;
    int it = bid >> 5, jt = bid & 31;
    int i0 = it * 64, j0 = jt * 64;
    int tid = threadIdx.x;

    {
        int b = tid >> 6, r = tid & 63;
        const float* ap = &yg[((size_t)(b * M_ + i0 + r)) * 3];
        la4[tid] = make_float4(ap[0], ap[1], ap[2], 0.f);
        const float* bp = &yg[((size_t)(b * M_ + j0 + r)) * 3];
        lb4[tid] = make_float4(bp[0], bp[1], bp[2], 0.f);
    }
    __syncthreads();

    int tj = tid & 15, ti = tid >> 4;
    float tcs[4][4];
#pragma unroll
    for (int a = 0; a < 4; a++) {
        const float* tr = &Ts[((size_t)(i0 + ti * 4 + a)) * M_ + j0 + tj];
#pragma unroll
        for (int jj = 0; jj < 4; jj++) tcs[a][jj] = tr[jj * 16];
    }
    float s_tpl = 0.f;
#pragma unroll
    for (int b = 0; b < B_; b++) {
        float4 row[4], col[4];
#pragma unroll
        for (int a = 0; a < 4; a++) row[a] = la4[b * 64 + ti * 4 + a];
#pragma unroll
        for (int jj = 0; jj < 4; jj++) col[jj] = lb4[b * 64 + jj * 16 + tj];
#pragma unroll
        for (int jj = 0; jj < 4; jj++)
#pragma unroll
            for (int a = 0; a < 4; a++) {
                float dx = row[a].x - col[jj].x;
                float dy = row[a].y - col[jj].y;
                float dz = row[a].z - col[jj].z;
                float d2 = fmaf(dz, dz, fmaf(dy, dy, dx * dx));
                float r  = __builtin_amdgcn_sqrtf(d2);
                float s  = r - tcs[a][jj];
                s_tpl = fmaf(s, s, s_tpl);
            }
    }
    double dt = (double)s_tpl;
    for (int off = 32; off; off >>= 1) dt += __shfl_down(dt, off);
    if ((tid & 63) == 0) wred[tid >> 6] = dt;
    __syncthreads();
    if (tid == 0) pyy[bid] = (wred[0] + wred[1]) + (wred[2] + wred[3]);
}

// ---------------------------------------------------------------- chamfer one side
__global__ __launch_bounds__(256) void k_chamfer(const float* __restrict__ A,
                                                 const float* __restrict__ Bsd,
                                                 unsigned* outmin) {
    __shared__ float4 lb[128];
    int bid = blockIdx.x;
    int rc = bid >> 4;
    int jc = bid & 15;
    int row = rc * 256 + threadIdx.x;
    int b = row >> 11;
    int j0 = jc * 128;

    for (int t = threadIdx.x; t < 128 * 3; t += 256) {
        int j = t / 3, c = t % 3;
        ((float*)&lb[j])[c] = Bsd[((size_t)(b * 2048 + j0 + j)) * 3 + c];
    }
    __syncthreads();

    const float* p = &A[(size_t)row * 3];
    float ax = p[0], ay = p[1], az = p[2];
    float m2 = __uint_as_float(0x7F800000u);
#pragma unroll 4
    for (int j = 0; j < 128; j++) {
        float4 pv = lb[j];
        float dx = ax - pv.x, dy = ay - pv.y, dz = az - pv.z;
        m2 = fminf(m2, fmaf(dz, dz, fmaf(dy, dy, dx * dx)));
    }
    atomicMin(&outmin[row], __float_as_uint(m2));
}

// ---------------------------------------------------------------- final combine
__global__ __launch_bounds__(256) void k_final(const unsigned* __restrict__ rowmin,
                                               const unsigned* __restrict__ colmin,
                                               const double* __restrict__ pT,
                                               const double* __restrict__ pE,
                                               const double* __restrict__ pV,
                                               const double* __restrict__ pyy,
                                               const double* __restrict__ pvq,
                                               float* out) {
    __shared__ double sh[6][256];
    int tid = threadIdx.x;
    double sc = 0.0, sT = 0.0, sE = 0.0, sV = 0.0, sY = 0.0, sQ = 0.0;
    for (int i = tid; i < B_ * N_; i += 256) sc += (double)__builtin_amdgcn_sqrtf(__uint_as_float(rowmin[i]));
    for (int i = tid; i < B_ * M_; i += 256) sc += (double)__builtin_amdgcn_sqrtf(__uint_as_float(colmin[i]));
    for (int i = tid; i < 2048; i += 256) { sT += pT[i]; sE += pE[i]; sV += pV[i]; sQ += pvq[i]; }
    for (int i = tid; i < 1024; i += 256) sY += pyy[i];
    sh[0][tid] = sc; sh[1][tid] = sT; sh[2][tid] = sE;
    sh[3][tid] = sV; sh[4][tid] = sY; sh[5][tid] = sQ;
    __syncthreads();
    for (int st = 128; st; st >>= 1) {
        if (tid < st)
#pragma unroll
            for (int q = 0; q < 6; q++) sh[q][tid] += sh[q][tid + st];
        __syncthreads();
    }
    if (tid == 0) {
        double chamfer = sh[0][0] / (double)(B_ * N_);
        double vq  = 1.25 * sh[5][0] / (double)((size_t)B_ * M_ * D_);
        double tyy = sh[4][0] / (double)((size_t)B_ * M_ * M_);
        double tcr = sh[1][0] / (double)((size_t)B_ * M_ * M2_);
        double el  = 0.1 * (sh[2][0] + sh[3][0]) / (double)B_;
        out[0] = (float)(chamfer + vq + tyy + tcr + el);
    }
}

// ---------------------------------------------------------------- launch
extern "C" void kernel_launch(void* const* d_in, const int* in_sizes, int n_in,
                              void* d_out, int out_size, void* d_ws, size_t ws_size,
                              hipStream_t stream) {
    const float* x   = (const float*)d_in[0];
    const float* y   = (const float*)d_in[1];
    const float* enc = (const float*)d_in[2];
    const float* pc  = (const float*)d_in[3];
    const float* sf  = (const float*)d_in[4];
    const float* pf  = (const float*)d_in[5];
    const float* Ts  = (const float*)d_in[6];
    const float* Tc  = (const float*)d_in[7];
    const float* emb = (const float*)d_in[8];
    float* out = (float*)d_out;

    char* ws = (char*)d_ws;
    unsigned* rowmin         = (unsigned*)(ws + 0);       // 8192 u32  (32 KB)
    unsigned* colmin         = (unsigned*)(ws + 32768);   // 8192 u32  (32 KB)
    float* lq                = (float*)(ws + 65536);      // 8192 f32  (32 KB)
    float* pq                = (float*)(ws + 98304);      // 16384 f32 (64 KB)
    float* e2                = (float*)(ws + 163840);     // 512 f32   (2 KB)
    unsigned long long* vqb  = (unsigned long long*)(ws + 166144); // 8192 u64 (64 KB)
    double* pT               = (double*)(ws + 231680);    // 2048 f64 (16 KB)
    double* pE               = (double*)(ws + 248064);    // 2048 f64
    double* pV               = (double*)(ws + 264448);    // 2048 f64
    double* pvq              = (double*)(ws + 280832);    // 2048 f64
    double* pyy              = (double*)(ws + 297216);    // 1024 f64 (8 KB) -> end 305408

    hipLaunchKernelGGL(k_init, dim3(32), dim3(256), 0, stream, rowmin, colmin, vqb);
    hipLaunchKernelGGL(k_prep, dim3(98), dim3(256), 0, stream, emb, sf, pf, e2, lq, pq);
    hipLaunchKernelGGL(k_vq, dim3(256), dim3(256), 0, stream, enc, emb, e2, vqb);
    hipLaunchKernelGGL(k_vqep, dim3(2048), dim3(256), 0, stream, enc, emb, vqb, pvq);
    hipLaunchKernelGGL(k_cross, dim3(2048), dim3(256), 0, stream, y, pc, Tc, lq, pq, pT, pE, pV);
    hipLaunchKernelGGL(k_yy, dim3(1024), dim3(256), 0, stream, y, Ts, pyy);
    hipLaunchKernelGGL(k_chamfer, dim3(512), dim3(256), 0, stream, x, y, rowmin);
    hipLaunchKernelGGL(k_chamfer, dim3(512), dim3(256), 0, stream, y, x, colmin);
    hipLaunchKernelGGL(k_final, dim3(1), dim3(256), 0, stream, rowmin, colmin,
                       pT, pE, pV, pyy, pvq, out);
}

// Round 8
// 176.851 us; speedup vs baseline: 3.5644x; 1.1724x over previous
//
#include <hip/hip_runtime.h>

#define B_ 4
#define N_ 2048
#define M_ 2048
#define M2_ 4096
#define D_ 128
#define K_ 512

__constant__ float LIGQ[10]  = {0.f,-0.3f,-0.4f,-0.1f,0.1f,-0.2f,-0.1f,-0.1f,-0.1f,0.1f};
__constant__ float PROTQ[4]  = {0.f,-0.3f,-0.4f,-0.2f};

// ---------------------------------------------------------------- setup: init + e2 + charges
__global__ __launch_bounds__(256) void k_setup(const float* __restrict__ emb,
                                               const float* __restrict__ sf,
                                               const float* __restrict__ pf,
                                               float* e2, float* lq, float* pq,
                                               unsigned* rowmin, unsigned* colmin,
                                               unsigned long long* vqbest) {
    int i = blockIdx.x * 256 + threadIdx.x;
    if (i < B_ * M_) {
        rowmin[i] = 0x7F800000u;
        colmin[i] = 0x7F800000u;
        vqbest[i] = 0xFFFFFFFFFFFFFFFFULL;
    }
    if (i < K_) {
        const float* e = emb + (size_t)i * D_;
        float s0 = 0.f, s1 = 0.f, s2 = 0.f, s3 = 0.f;
        for (int d = 0; d < D_; d += 4) {
            s0 = fmaf(e[d+0], e[d+0], s0);
            s1 = fmaf(e[d+1], e[d+1], s1);
            s2 = fmaf(e[d+2], e[d+2], s2);
            s3 = fmaf(e[d+3], e[d+3], s3);
        }
        e2[i] = (s0 + s1) + (s2 + s3);
    }
    int j = i - K_;
    if (j >= 0 && j < B_ * M_) {
        const float* f = sf + (size_t)j * D_;
        float best = f[0]; int bi = 0;
        for (int k = 1; k < 10; k++) { float v = f[k]; if (v > best) { best = v; bi = k; } }
        lq[j] = LIGQ[bi];
    }
    int p = i - K_ - B_ * M_;
    if (p >= 0 && p < B_ * M2_) {
        const float* f = pf + (size_t)p * D_;
        float best = f[0]; int bi = 0;
        for (int k = 1; k < 4; k++) { float v = f[k]; if (v > best) { best = v; bi = k; } }
        pq[p] = PROTQ[bi];
    }
}

// ---------------------------------------------------------------- VQ argmin GEMM
// 512 thr: 32(ti, 4 rows) x 16(tj, 8 cols); tile 128x128, K in 2 chunks of 64
__global__ __launch_bounds__(512) void k_vq(const float* __restrict__ enc,
                                            const float* __restrict__ emb,
                                            const float* __restrict__ e2g,
                                            unsigned long long* best) {
    __shared__ __align__(16) float lf[128 * 64];
    __shared__ __align__(16) float le[128 * 64];
    int bid = blockIdx.x;
    int rt = bid >> 2, ct = bid & 3;
    int r0 = rt * 128, c0 = ct * 128;
    int tid = threadIdx.x;
    int tj = tid & 15, ti = tid >> 4;      // ti 0..31

    float acc[4][8];
#pragma unroll
    for (int a = 0; a < 4; a++)
#pragma unroll
        for (int b = 0; b < 8; b++) acc[a][b] = 0.f;

    for (int kc = 0; kc < 2; kc++) {
        for (int v = tid; v < 128 * 16; v += 512) {
            int r  = v >> 4;
            int d4 = (v & 15) << 2;
            int dsw = d4 ^ (((r >> 3) & 7) << 2);
            *(float4*)&lf[r * 64 + dsw] = *(const float4*)&enc[((size_t)(r0 + r)) * D_ + kc * 64 + d4];
            *(float4*)&le[r * 64 + dsw] = *(const float4*)&emb[((size_t)(c0 + r)) * D_ + kc * 64 + d4];
        }
        __syncthreads();
        int fgrp = ((ti >> 1) & 7) << 2;
        int egrp = (tj & 7) << 2;
#pragma unroll 4
        for (int d4 = 0; d4 < 64; d4 += 4) {
            float4 fa[4], eb[8];
            int fsw = d4 ^ fgrp;
            int esw = d4 ^ egrp;
#pragma unroll
            for (int rr = 0; rr < 4; rr++) fa[rr] = *(float4*)&lf[(ti * 4 + rr) * 64 + fsw];
#pragma unroll
            for (int cc = 0; cc < 8; cc++) eb[cc] = *(float4*)&le[(tj * 8 + cc) * 64 + esw];
#pragma unroll
            for (int rr = 0; rr < 4; rr++)
#pragma unroll
                for (int cc = 0; cc < 8; cc++) {
                    acc[rr][cc] = fmaf(fa[rr].x, eb[cc].x, acc[rr][cc]);
                    acc[rr][cc] = fmaf(fa[rr].y, eb[cc].y, acc[rr][cc]);
                    acc[rr][cc] = fmaf(fa[rr].z, eb[cc].z, acc[rr][cc]);
                    acc[rr][cc] = fmaf(fa[rr].w, eb[cc].w, acc[rr][cc]);
                }
        }
        __syncthreads();
    }

    // per-row best over this block's 128 codes
    unsigned long long* red = (unsigned long long*)lf;    // 128*17*8 = 17.4 KB
#pragma unroll
    for (int rr = 0; rr < 4; rr++) {
        int r = ti * 4 + rr;
        float bs = __uint_as_float(0x7F800000u); int bidx = 0;
#pragma unroll
        for (int cc = 0; cc < 8; cc++) {
            int c = tj * 8 + cc;
            float s = e2g[c0 + c] - 2.f * acc[rr][cc];
            if (s < bs) { bs = s; bidx = c0 + c; }
        }
        unsigned ub = __float_as_uint(bs);
        ub = (ub & 0x80000000u) ? ~ub : (ub | 0x80000000u);
        red[r * 17 + tj] = ((unsigned long long)ub << 32) | (unsigned)bidx;
    }
    __syncthreads();
    if (tid < 128) {
        unsigned long long mn = red[tid * 17 + 0];
        for (int t = 1; t < 16; t++) {
            unsigned long long v = red[tid * 17 + t];
            mn = (v < mn) ? v : mn;
        }
        atomicMin(&best[r0 + tid], mn);
    }
}

// ---------------------------------------------------------------- mega: cross | yy | chamfer | vqep
// bid 0..2047 cross; 2048..3071 yy; 3072..4095 chamfer (x2); 4096..4351 vqep
__global__ __launch_bounds__(256) void k_mega(const float* __restrict__ x,
                                              const float* __restrict__ yg,
                                              const float* __restrict__ pg,
                                              const float* __restrict__ enc,
                                              const float* __restrict__ emb,
                                              const float* __restrict__ Ts,
                                              const float* __restrict__ Tc,
                                              const float* __restrict__ lq,
                                              const float* __restrict__ pq,
                                              const unsigned long long* __restrict__ vqb,
                                              unsigned* rowmin, unsigned* colmin,
                                              double* pT, double* pE, double* pV,
                                              double* pyy, double* pvq) {
    __shared__ __align__(16) char smem[8448];
    int bid = blockIdx.x;
    int tid = threadIdx.x;

    if (bid < 2048) {
        // ------------------ cross: tpl_cross + elec + vdw
        float4* lyq = (float4*)smem;               // 4 KB
        float4* lpq = (float4*)(smem + 4096);      // 4 KB
        double* wred = (double*)(smem + 8192);     // 96 B (3x4)
        int it = bid >> 6, jt = bid & 63;
        int i0 = it * 64, j0 = jt * 64;
        {
            int b = tid >> 6, r = tid & 63;
            const float* yp = &yg[((size_t)(b * M_ + i0 + r)) * 3];
            lyq[tid] = make_float4(yp[0], yp[1], yp[2], lq[b * M_ + i0 + r]);
            const float* pp = &pg[((size_t)(b * M2_ + j0 + r)) * 3];
            lpq[tid] = make_float4(pp[0], pp[1], pp[2], pq[b * M2_ + j0 + r]);
        }
        __syncthreads();

        int tj = tid & 15, ti = tid >> 4;
        float tcs[4][4];
#pragma unroll
        for (int a = 0; a < 4; a++) {
            const float* tr = &Tc[((size_t)(i0 + ti * 4 + a)) * M2_ + j0 + tj];
#pragma unroll
            for (int jj = 0; jj < 4; jj++) tcs[a][jj] = tr[jj * 16];
        }

        float s_tpl = 0.f, s_elec = 0.f, s_vdw = 0.f;
#pragma unroll
        for (int b = 0; b < B_; b++) {
            float4 row[4], col[4];
#pragma unroll
            for (int a = 0; a < 4; a++) row[a] = lyq[b * 64 + ti * 4 + a];
#pragma unroll
            for (int jj = 0; jj < 4; jj++) col[jj] = lpq[b * 64 + jj * 16 + tj];
#pragma unroll
            for (int jj = 0; jj < 4; jj++)
#pragma unroll
                for (int a = 0; a < 4; a++) {
                    float dx = row[a].x - col[jj].x;
                    float dy = row[a].y - col[jj].y;
                    float dz = row[a].z - col[jj].z;
                    float d2 = fmaf(dz, dz, fmaf(dy, dy, dx * dx));
                    float r  = __builtin_amdgcn_sqrtf(d2);
                    float s  = r - tcs[a][jj];
                    s_tpl = fmaf(s, s, s_tpl);
                    float dd  = r + 0.01f;
                    float inv = __builtin_amdgcn_rcpf(dd);
                    float i2 = inv * inv;
                    float i6 = i2 * i2 * i2;
                    s_vdw = fmaf(i6, i6 - 1.f, s_vdw);
                    s_elec = fmaf(row[a].w * col[jj].w, inv, s_elec);
                }
        }
        double dt = (double)s_tpl, de = (double)s_elec, dv = (double)s_vdw;
        for (int off = 32; off; off >>= 1) {
            dt += __shfl_down(dt, off);
            de += __shfl_down(de, off);
            dv += __shfl_down(dv, off);
        }
        int wv = tid >> 6;
        if ((tid & 63) == 0) { wred[wv] = dt; wred[4 + wv] = de; wred[8 + wv] = dv; }
        __syncthreads();
        if (tid == 0) {
            pT[bid] = (wred[0] + wred[1]) + (wred[2] + wred[3]);
            pE[bid] = (wred[4] + wred[5]) + (wred[6] + wred[7]);
            pV[bid] = (wred[8] + wred[9]) + (wred[10] + wred[11]);
        }
    } else if (bid < 3072) {
        // ------------------ yy: tpl_scaffold
        int sb = bid - 2048;
        float4* la4 = (float4*)smem;
        float4* lb4 = (float4*)(smem + 4096);
        double* wred = (double*)(smem + 8192);
        int it = sb >> 5, jt = sb & 31;
        int i0 = it * 64, j0 = jt * 64;
        {
            int b = tid >> 6, r = tid & 63;
            const float* ap = &yg[((size_t)(b * M_ + i0 + r)) * 3];
            la4[tid] = make_float4(ap[0], ap[1], ap[2], 0.f);
            const float* bp = &yg[((size_t)(b * M_ + j0 + r)) * 3];
            lb4[tid] = make_float4(bp[0], bp[1], bp[2], 0.f);
        }
        __syncthreads();

        int tj = tid & 15, ti = tid >> 4;
        float tcs[4][4];
#pragma unroll
        for (int a = 0; a < 4; a++) {
            const float* tr = &Ts[((size_t)(i0 + ti * 4 + a)) * M_ + j0 + tj];
#pragma unroll
            for (int jj = 0; jj < 4; jj++) tcs[a][jj] = tr[jj * 16];
        }
        float s_tpl = 0.f;
#pragma unroll
        for (int b = 0; b < B_; b++) {
            float4 row[4], col[4];
#pragma unroll
            for (int a = 0; a < 4; a++) row[a] = la4[b * 64 + ti * 4 + a];
#pragma unroll
            for (int jj = 0; jj < 4; jj++) col[jj] = lb4[b * 64 + jj * 16 + tj];
#pragma unroll
            for (int jj = 0; jj < 4; jj++)
#pragma unroll
                for (int a = 0; a < 4; a++) {
                    float dx = row[a].x - col[jj].x;
                    float dy = row[a].y - col[jj].y;
                    float dz = row[a].z - col[jj].z;
                    float d2 = fmaf(dz, dz, fmaf(dy, dy, dx * dx));
                    float r  = __builtin_amdgcn_sqrtf(d2);
                    float s  = r - tcs[a][jj];
                    s_tpl = fmaf(s, s, s_tpl);
                }
        }
        double dt = (double)s_tpl;
        for (int off = 32; off; off >>= 1) dt += __shfl_down(dt, off);
        if ((tid & 63) == 0) wred[tid >> 6] = dt;
        __syncthreads();
        if (tid == 0) pyy[sb] = (wred[0] + wred[1]) + (wred[2] + wred[3]);
    } else if (bid < 4096) {
        // ------------------ chamfer (both sides)
        int sub = bid - 3072;
        const float* A; const float* Bsd; unsigned* outmin;
        if (sub < 512) { A = x;  Bsd = yg; outmin = rowmin; }
        else           { A = yg; Bsd = x;  outmin = colmin; sub -= 512; }
        float4* lb = (float4*)smem;
        int rc = sub >> 4;
        int jc = sub & 15;
        int row = rc * 256 + tid;
        int b = row >> 11;
        int j0 = jc * 128;

        for (int t = tid; t < 128 * 3; t += 256) {
            int j = t / 3, c = t % 3;
            ((float*)&lb[j])[c] = Bsd[((size_t)(b * 2048 + j0 + j)) * 3 + c];
        }
        __syncthreads();

        const float* p = &A[(size_t)row * 3];
        float ax = p[0], ay = p[1], az = p[2];
        float m2 = __uint_as_float(0x7F800000u);
#pragma unroll 4
        for (int j = 0; j < 128; j++) {
            float4 pv = lb[j];
            float dx = ax - pv.x, dy = ay - pv.y, dz = az - pv.z;
            m2 = fminf(m2, fmaf(dz, dz, fmaf(dy, dy, dx * dx)));
        }
        atomicMin(&outmin[row], __float_as_uint(m2));
    } else {
        // ------------------ vqep: VQ MSE, 32 rows per block
        double* sred = (double*)smem;
        int base = (bid - 4096) * 32;
        int wv = tid >> 6, lane = tid & 63;
        double s = 0.0;
#pragma unroll
        for (int it = 0; it < 8; it++) {
            int w = base + wv * 8 + it;
            int idx = (int)(vqb[w] & 0xFFFFFFFFu);
            float2 fv = *(const float2*)&enc[(size_t)w * D_ + lane * 2];
            float2 ev = *(const float2*)&emb[(size_t)idx * D_ + lane * 2];
            float d0 = ev.x - fv.x, d1 = ev.y - fv.y;
            s += (double)(d0 * d0) + (double)(d1 * d1);
        }
        for (int off = 32; off; off >>= 1) s += __shfl_down(s, off);
        if (lane == 0) sred[wv] = s;
        __syncthreads();
        if (tid == 0) pvq[bid - 4096] = (sred[0] + sred[1]) + (sred[2] + sred[3]);
    }
}

// ---------------------------------------------------------------- final combine
__global__ __launch_bounds__(1024) void k_final(const unsigned* __restrict__ rowmin,
                                                const unsigned* __restrict__ colmin,
                                                const double* __restrict__ pT,
                                                const double* __restrict__ pE,
                                                const double* __restrict__ pV,
                                                const double* __restrict__ pyy,
                                                const double* __restrict__ pvq,
                                                float* out) {
    __shared__ double sh[6][1024];
    int tid = threadIdx.x;
    double sc = 0.0, sT = 0.0, sE = 0.0, sV = 0.0, sY = 0.0, sQ = 0.0;
    for (int i = tid; i < B_ * N_; i += 1024) sc += (double)__builtin_amdgcn_sqrtf(__uint_as_float(rowmin[i]));
    for (int i = tid; i < B_ * M_; i += 1024) sc += (double)__builtin_amdgcn_sqrtf(__uint_as_float(colmin[i]));
    for (int i = tid; i < 2048; i += 1024) { sT += pT[i]; sE += pE[i]; sV += pV[i]; }
    if (tid < 1024) { int i = tid; if (i < 1024) sY += pyy[i]; }
    if (tid < 256) sQ = pvq[tid];
    sh[0][tid] = sc; sh[1][tid] = sT; sh[2][tid] = sE;
    sh[3][tid] = sV; sh[4][tid] = sY; sh[5][tid] = sQ;
    __syncthreads();
    for (int st = 512; st; st >>= 1) {
        if (tid < st)
#pragma unroll
            for (int q = 0; q < 6; q++) sh[q][tid] += sh[q][tid + st];
        __syncthreads();
    }
    if (tid == 0) {
        double chamfer = sh[0][0] / (double)(B_ * N_);
        double vq  = 1.25 * sh[5][0] / (double)((size_t)B_ * M_ * D_);
        double tyy = sh[4][0] / (double)((size_t)B_ * M_ * M_);
        double tcr = sh[1][0] / (double)((size_t)B_ * M_ * M2_);
        double el  = 0.1 * (sh[2][0] + sh[3][0]) / (double)B_;
        out[0] = (float)(chamfer + vq + tyy + tcr + el);
    }
}

// ---------------------------------------------------------------- launch
extern "C" void kernel_launch(void* const* d_in, const int* in_sizes, int n_in,
                              void* d_out, int out_size, void* d_ws, size_t ws_size,
                              hipStream_t stream) {
    const float* x   = (const float*)d_in[0];
    const float* y   = (const float*)d_in[1];
    const float* enc = (const float*)d_in[2];
    const float* pc  = (const float*)d_in[3];
    const float* sf  = (const float*)d_in[4];
    const float* pf  = (const float*)d_in[5];
    const float* Ts  = (const float*)d_in[6];
    const float* Tc  = (const float*)d_in[7];
    const float* emb = (const float*)d_in[8];
    float* out = (float*)d_out;

    char* ws = (char*)d_ws;
    unsigned* rowmin         = (unsigned*)(ws + 0);
    unsigned* colmin         = (unsigned*)(ws + 32768);
    float* lq                = (float*)(ws + 65536);
    float* pq                = (float*)(ws + 98304);
    float* e2                = (float*)(ws + 163840);
    unsigned long long* vqb  = (unsigned long long*)(ws + 166144);
    double* pT               = (double*)(ws + 231680);
    double* pE               = (double*)(ws + 248064);
    double* pV               = (double*)(ws + 264448);
    double* pvq              = (double*)(ws + 280832);
    double* pyy              = (double*)(ws + 297216);

    hipLaunchKernelGGL(k_setup, dim3(98), dim3(256), 0, stream,
                       emb, sf, pf, e2, lq, pq, rowmin, colmin, vqb);
    hipLaunchKernelGGL(k_vq, dim3(256), dim3(512), 0, stream, enc, emb, e2, vqb);
    hipLaunchKernelGGL(k_mega, dim3(4352), dim3(256), 0, stream,
                       x, y, pc, enc, emb, Ts, Tc, lq, pq, vqb,
                       rowmin, colmin, pT, pE, pV, pyy, pvq);
    hipLaunchKernelGGL(k_final, dim3(1), dim3(1024), 0, stream, rowmin, colmin,
                       pT, pE, pV, pyy, pvq, out);
}

// Round 9
// 171.630 us; speedup vs baseline: 3.6728x; 1.0304x over previous
//
#include <hip/hip_runtime.h>

#define B_ 4
#define N_ 2048
#define M_ 2048
#define M2_ 4096
#define D_ 128
#define K_ 512

__constant__ float LIGQ[10]  = {0.f,-0.3f,-0.4f,-0.1f,0.1f,-0.2f,-0.1f,-0.1f,-0.1f,0.1f};
__constant__ float PROTQ[4]  = {0.f,-0.3f,-0.4f,-0.2f};

// ---------------------------------------------------------------- VQ argmin GEMM + absorbed setup
// blocks 0..255: 128x128 tile VQ scoring (512 thr = 32 ti x 16 tj, 4x8 acc)
// blocks 256..271: lq argmax; 272..303: pq argmax; 304..319: rowmin/colmin init
__global__ __launch_bounds__(512) void k_vq(const float* __restrict__ enc,
                                            const float* __restrict__ emb,
                                            const float* __restrict__ sf,
                                            const float* __restrict__ pf,
                                            float* lq, float* pq,
                                            unsigned* rowmin, unsigned* colmin,
                                            unsigned long long* vqbPart) {
    __shared__ __align__(16) float lf[128 * 64];
    __shared__ __align__(16) float le[128 * 64];
    __shared__ float e2s[128];
    int bid = blockIdx.x;
    int tid = threadIdx.x;

    if (bid >= 256) {
        int sb = bid - 256;
        if (sb < 16) {                      // lq: ligand charges, 512 rows/block
            int j = sb * 512 + tid;
            const float* f = sf + (size_t)j * D_;
            float4 v0 = *(const float4*)f;
            float4 v1 = *(const float4*)(f + 4);
            float2 v2 = *(const float2*)(f + 8);
            float best = v0.x; int bi = 0;
            if (v0.y > best) { best = v0.y; bi = 1; }
            if (v0.z > best) { best = v0.z; bi = 2; }
            if (v0.w > best) { best = v0.w; bi = 3; }
            if (v1.x > best) { best = v1.x; bi = 4; }
            if (v1.y > best) { best = v1.y; bi = 5; }
            if (v1.z > best) { best = v1.z; bi = 6; }
            if (v1.w > best) { best = v1.w; bi = 7; }
            if (v2.x > best) { best = v2.x; bi = 8; }
            if (v2.y > best) { best = v2.y; bi = 9; }
            lq[j] = LIGQ[bi];
        } else if (sb < 48) {               // pq: protein charges
            int p = (sb - 16) * 512 + tid;
            float4 v0 = *(const float4*)(pf + (size_t)p * D_);
            float best = v0.x; int bi = 0;
            if (v0.y > best) { best = v0.y; bi = 1; }
            if (v0.z > best) { best = v0.z; bi = 2; }
            if (v0.w > best) { best = v0.w; bi = 3; }
            pq[p] = PROTQ[bi];
        } else {                            // init chamfer mins
            int i = (sb - 48) * 512 + tid;
            rowmin[i] = 0x7F800000u;
            colmin[i] = 0x7F800000u;
        }
        return;
    }

    int rt = bid >> 2, ct = bid & 3;
    int r0 = rt * 128, c0 = ct * 128;
    int tj = tid & 15, ti = tid >> 4;      // ti 0..31

    // in-block e2 for this block's 128 codes (overlaps with staging)
    float e2r = 0.f;
    if (tid < 128) {
        const float* e = emb + (size_t)(c0 + tid) * D_;
        float s0 = 0.f, s1 = 0.f, s2 = 0.f, s3 = 0.f;
        for (int d = 0; d < D_; d += 4) {
            float4 v = *(const float4*)&e[d];
            s0 = fmaf(v.x, v.x, s0);
            s1 = fmaf(v.y, v.y, s1);
            s2 = fmaf(v.z, v.z, s2);
            s3 = fmaf(v.w, v.w, s3);
        }
        e2r = (s0 + s1) + (s2 + s3);
    }

    float acc[4][8];
#pragma unroll
    for (int a = 0; a < 4; a++)
#pragma unroll
        for (int b = 0; b < 8; b++) acc[a][b] = 0.f;

    for (int kc = 0; kc < 2; kc++) {
        for (int v = tid; v < 128 * 16; v += 512) {
            int r  = v >> 4;
            int d4 = (v & 15) << 2;
            int dsw = d4 ^ (((r >> 3) & 7) << 2);
            *(float4*)&lf[r * 64 + dsw] = *(const float4*)&enc[((size_t)(r0 + r)) * D_ + kc * 64 + d4];
            *(float4*)&le[r * 64 + dsw] = *(const float4*)&emb[((size_t)(c0 + r)) * D_ + kc * 64 + d4];
        }
        __syncthreads();
        int fgrp = ((ti >> 1) & 7) << 2;
        int egrp = (tj & 7) << 2;
#pragma unroll 4
        for (int d4 = 0; d4 < 64; d4 += 4) {
            float4 fa[4], eb[8];
            int fsw = d4 ^ fgrp;
            int esw = d4 ^ egrp;
#pragma unroll
            for (int rr = 0; rr < 4; rr++) fa[rr] = *(float4*)&lf[(ti * 4 + rr) * 64 + fsw];
#pragma unroll
            for (int cc = 0; cc < 8; cc++) eb[cc] = *(float4*)&le[(tj * 8 + cc) * 64 + esw];
#pragma unroll
            for (int rr = 0; rr < 4; rr++)
#pragma unroll
                for (int cc = 0; cc < 8; cc++) {
                    acc[rr][cc] = fmaf(fa[rr].x, eb[cc].x, acc[rr][cc]);
                    acc[rr][cc] = fmaf(fa[rr].y, eb[cc].y, acc[rr][cc]);
                    acc[rr][cc] = fmaf(fa[rr].z, eb[cc].z, acc[rr][cc]);
                    acc[rr][cc] = fmaf(fa[rr].w, eb[cc].w, acc[rr][cc]);
                }
        }
        __syncthreads();
    }

    if (tid < 128) e2s[tid] = e2r;
    __syncthreads();

    // per-row best over this block's 128 codes; pack (orderable score | idx)
    unsigned long long* red = (unsigned long long*)lf;    // 17.4 KB
#pragma unroll
    for (int rr = 0; rr < 4; rr++) {
        int r = ti * 4 + rr;
        float bs = __uint_as_float(0x7F800000u); int bidx = 0;
#pragma unroll
        for (int cc = 0; cc < 8; cc++) {
            int c = tj * 8 + cc;
            float s = e2s[c] - 2.f * acc[rr][cc];
            if (s < bs) { bs = s; bidx = c0 + c; }
        }
        unsigned ub = __float_as_uint(bs);
        ub = (ub & 0x80000000u) ? ~ub : (ub | 0x80000000u);
        red[r * 17 + tj] = ((unsigned long long)ub << 32) | (unsigned)bidx;
    }
    __syncthreads();
    if (tid < 128) {
        unsigned long long mn = red[tid * 17 + 0];
        for (int t = 1; t < 16; t++) {
            unsigned long long v = red[tid * 17 + t];
            mn = (v < mn) ? v : mn;
        }
        vqbPart[ct * 8192 + r0 + tid] = mn;   // plain store, no atomics
    }
}

// ---------------------------------------------------------------- mega: cross | yy | chamfer | vqep
// virtual id vb = transpose(bid) interleaves sections for CU packing
__global__ __launch_bounds__(256) void k_mega(const float* __restrict__ x,
                                              const float* __restrict__ yg,
                                              const float* __restrict__ pg,
                                              const float* __restrict__ enc,
                                              const float* __restrict__ emb,
                                              const float* __restrict__ Ts,
                                              const float* __restrict__ Tc,
                                              const float* __restrict__ lq,
                                              const float* __restrict__ pq,
                                              const unsigned long long* __restrict__ vqbPart,
                                              unsigned* rowmin, unsigned* colmin,
                                              double* pT, double* pE, double* pV,
                                              double* pyy, double* pvq) {
    __shared__ __align__(16) char smem[8448];
    int bid0 = blockIdx.x;
    int vb = (bid0 & 127) * 34 + (bid0 >> 7);   // bijection on [0,4352)
    int tid = threadIdx.x;

    if (vb < 2048) {
        // ------------------ cross: tpl_cross + elec + vdw
        float4* lyq = (float4*)smem;
        float4* lpq = (float4*)(smem + 4096);
        double* wred = (double*)(smem + 8192);
        int it = vb >> 6, jt = vb & 63;
        int i0 = it * 64, j0 = jt * 64;
        {
            int b = tid >> 6, r = tid & 63;
            const float* yp = &yg[((size_t)(b * M_ + i0 + r)) * 3];
            lyq[tid] = make_float4(yp[0], yp[1], yp[2], lq[b * M_ + i0 + r]);
            const float* pp = &pg[((size_t)(b * M2_ + j0 + r)) * 3];
            lpq[tid] = make_float4(pp[0], pp[1], pp[2], pq[b * M2_ + j0 + r]);
        }
        __syncthreads();

        int tj = tid & 15, ti = tid >> 4;
        float tcs[4][4];
#pragma unroll
        for (int a = 0; a < 4; a++) {
            const float* tr = &Tc[((size_t)(i0 + ti * 4 + a)) * M2_ + j0 + tj];
#pragma unroll
            for (int jj = 0; jj < 4; jj++) tcs[a][jj] = tr[jj * 16];
        }

        float s_tpl = 0.f, s_elec = 0.f, s_vdw = 0.f;
#pragma unroll
        for (int b = 0; b < B_; b++) {
            float4 row[4], col[4];
#pragma unroll
            for (int a = 0; a < 4; a++) row[a] = lyq[b * 64 + ti * 4 + a];
#pragma unroll
            for (int jj = 0; jj < 4; jj++) col[jj] = lpq[b * 64 + jj * 16 + tj];
#pragma unroll
            for (int jj = 0; jj < 4; jj++)
#pragma unroll
                for (int a = 0; a < 4; a++) {
                    float dx = row[a].x - col[jj].x;
                    float dy = row[a].y - col[jj].y;
                    float dz = row[a].z - col[jj].z;
                    float d2 = fmaf(dz, dz, fmaf(dy, dy, dx * dx));
                    float r  = __builtin_amdgcn_sqrtf(d2);
                    float s  = r - tcs[a][jj];
                    s_tpl = fmaf(s, s, s_tpl);
                    float dd  = r + 0.01f;
                    float inv = __builtin_amdgcn_rcpf(dd);
                    float i2 = inv * inv;
                    float i6 = i2 * i2 * i2;
                    s_vdw = fmaf(i6, i6 - 1.f, s_vdw);
                    s_elec = fmaf(row[a].w * col[jj].w, inv, s_elec);
                }
        }
        double dt = (double)s_tpl, de = (double)s_elec, dv = (double)s_vdw;
        for (int off = 32; off; off >>= 1) {
            dt += __shfl_down(dt, off);
            de += __shfl_down(de, off);
            dv += __shfl_down(dv, off);
        }
        int wv = tid >> 6;
        if ((tid & 63) == 0) { wred[wv] = dt; wred[4 + wv] = de; wred[8 + wv] = dv; }
        __syncthreads();
        if (tid == 0) {
            pT[vb] = (wred[0] + wred[1]) + (wred[2] + wred[3]);
            pE[vb] = (wred[4] + wred[5]) + (wred[6] + wred[7]);
            pV[vb] = (wred[8] + wred[9]) + (wred[10] + wred[11]);
        }
    } else if (vb < 3072) {
        // ------------------ yy: tpl_scaffold
        int sb = vb - 2048;
        float4* la4 = (float4*)smem;
        float4* lb4 = (float4*)(smem + 4096);
        double* wred = (double*)(smem + 8192);
        int it = sb >> 5, jt = sb & 31;
        int i0 = it * 64, j0 = jt * 64;
        {
            int b = tid >> 6, r = tid & 63;
            const float* ap = &yg[((size_t)(b * M_ + i0 + r)) * 3];
            la4[tid] = make_float4(ap[0], ap[1], ap[2], 0.f);
            const float* bp = &yg[((size_t)(b * M_ + j0 + r)) * 3];
            lb4[tid] = make_float4(bp[0], bp[1], bp[2], 0.f);
        }
        __syncthreads();

        int tj = tid & 15, ti = tid >> 4;
        float tcs[4][4];
#pragma unroll
        for (int a = 0; a < 4; a++) {
            const float* tr = &Ts[((size_t)(i0 + ti * 4 + a)) * M_ + j0 + tj];
#pragma unroll
            for (int jj = 0; jj < 4; jj++) tcs[a][jj] = tr[jj * 16];
        }
        float s_tpl = 0.f;
#pragma unroll
        for (int b = 0; b < B_; b++) {
            float4 row[4], col[4];
#pragma unroll
            for (int a = 0; a < 4; a++) row[a] = la4[b * 64 + ti * 4 + a];
#pragma unroll
            for (int jj = 0; jj < 4; jj++) col[jj] = lb4[b * 64 + jj * 16 + tj];
#pragma unroll
            for (int jj = 0; jj < 4; jj++)
#pragma unroll
                for (int a = 0; a < 4; a++) {
                    float dx = row[a].x - col[jj].x;
                    float dy = row[a].y - col[jj].y;
                    float dz = row[a].z - col[jj].z;
                    float d2 = fmaf(dz, dz, fmaf(dy, dy, dx * dx));
                    float r  = __builtin_amdgcn_sqrtf(d2);
                    float s  = r - tcs[a][jj];
                    s_tpl = fmaf(s, s, s_tpl);
                }
        }
        double dt = (double)s_tpl;
        for (int off = 32; off; off >>= 1) dt += __shfl_down(dt, off);
        if ((tid & 63) == 0) wred[tid >> 6] = dt;
        __syncthreads();
        if (tid == 0) pyy[sb] = (wred[0] + wred[1]) + (wred[2] + wred[3]);
    } else if (vb < 4096) {
        // ------------------ chamfer (both sides)
        int sub = vb - 3072;
        const float* A; const float* Bsd; unsigned* outmin;
        if (sub < 512) { A = x;  Bsd = yg; outmin = rowmin; }
        else           { A = yg; Bsd = x;  outmin = colmin; sub -= 512; }
        float4* lb = (float4*)smem;
        int rc = sub >> 4;
        int jc = sub & 15;
        int row = rc * 256 + tid;
        int b = row >> 11;
        int j0 = jc * 128;

        for (int t = tid; t < 128 * 3; t += 256) {
            int j = t / 3, c = t % 3;
            ((float*)&lb[j])[c] = Bsd[((size_t)(b * 2048 + j0 + j)) * 3 + c];
        }
        __syncthreads();

        const float* p = &A[(size_t)row * 3];
        float ax = p[0], ay = p[1], az = p[2];
        float m2 = __uint_as_float(0x7F800000u);
#pragma unroll 4
        for (int j = 0; j < 128; j++) {
            float4 pv = lb[j];
            float dx = ax - pv.x, dy = ay - pv.y, dz = az - pv.z;
            m2 = fminf(m2, fmaf(dz, dz, fmaf(dy, dy, dx * dx)));
        }
        atomicMin(&outmin[row], __float_as_uint(m2));
    } else {
        // ------------------ vqep: VQ MSE, 32 rows per block; argmin = min of 4 partials
        double* sred = (double*)smem;
        int base = (vb - 4096) * 32;
        int wv = tid >> 6, lane = tid & 63;
        double s = 0.0;
#pragma unroll
        for (int it = 0; it < 8; it++) {
            int w = base + wv * 8 + it;
            unsigned long long m0 = vqbPart[w];
            unsigned long long m1 = vqbPart[8192 + w];
            unsigned long long m2_ = vqbPart[16384 + w];
            unsigned long long m3 = vqbPart[24576 + w];
            m0 = (m1 < m0) ? m1 : m0;
            m2_ = (m3 < m2_) ? m3 : m2_;
            m0 = (m2_ < m0) ? m2_ : m0;
            int idx = (int)(m0 & 0xFFFFFFFFu);
            float2 fv = *(const float2*)&enc[(size_t)w * D_ + lane * 2];
            float2 ev = *(const float2*)&emb[(size_t)idx * D_ + lane * 2];
            float d0 = ev.x - fv.x, d1 = ev.y - fv.y;
            s += (double)(d0 * d0) + (double)(d1 * d1);
        }
        for (int off = 32; off; off >>= 1) s += __shfl_down(s, off);
        if (lane == 0) sred[wv] = s;
        __syncthreads();
        if (tid == 0) pvq[vb - 4096] = (sred[0] + sred[1]) + (sred[2] + sred[3]);
    }
}

// ---------------------------------------------------------------- final combine (vectorized reads)
__global__ __launch_bounds__(1024) void k_final(const unsigned* __restrict__ rowmin,
                                                const unsigned* __restrict__ colmin,
                                                const double* __restrict__ pT,
                                                const double* __restrict__ pE,
                                                const double* __restrict__ pV,
                                                const double* __restrict__ pyy,
                                                const double* __restrict__ pvq,
                                                float* out) {
    __shared__ double sh[6][1024];
    int tid = threadIdx.x;
    double sc = 0.0, sT = 0.0, sE = 0.0, sV = 0.0, sY = 0.0, sQ = 0.0;
    for (int i = tid; i < 2048; i += 1024) {            // 8192 u32 as 2048 uint4
        uint4 v = ((const uint4*)rowmin)[i];
        sc += (double)__builtin_amdgcn_sqrtf(__uint_as_float(v.x))
            + (double)__builtin_amdgcn_sqrtf(__uint_as_float(v.y))
            + (double)__builtin_amdgcn_sqrtf(__uint_as_float(v.z))
            + (double)__builtin_amdgcn_sqrtf(__uint_as_float(v.w));
        uint4 w = ((const uint4*)colmin)[i];
        sc += (double)__builtin_amdgcn_sqrtf(__uint_as_float(w.x))
            + (double)__builtin_amdgcn_sqrtf(__uint_as_float(w.y))
            + (double)__builtin_amdgcn_sqrtf(__uint_as_float(w.z))
            + (double)__builtin_amdgcn_sqrtf(__uint_as_float(w.w));
    }
    {
        double2 a = ((const double2*)pT)[tid];  sT += a.x + a.y;   // 2048 doubles = 1024 double2
        double2 b = ((const double2*)pE)[tid];  sE += b.x + b.y;
        double2 c = ((const double2*)pV)[tid];  sV += c.x + c.y;
        sY += pyy[tid];
        if (tid < 256) sQ = pvq[tid];
    }
    sh[0][tid] = sc; sh[1][tid] = sT; sh[2][tid] = sE;
    sh[3][tid] = sV; sh[4][tid] = sY; sh[5][tid] = sQ;
    __syncthreads();
    for (int st = 512; st; st >>= 1) {
        if (tid < st)
#pragma unroll
            for (int q = 0; q < 6; q++) sh[q][tid] += sh[q][tid + st];
        __syncthreads();
    }
    if (tid == 0) {
        double chamfer = sh[0][0] / (double)(B_ * N_);
        double vq  = 1.25 * sh[5][0] / (double)((size_t)B_ * M_ * D_);
        double tyy = sh[4][0] / (double)((size_t)B_ * M_ * M_);
        double tcr = sh[1][0] / (double)((size_t)B_ * M_ * M2_);
        double el  = 0.1 * (sh[2][0] + sh[3][0]) / (double)B_;
        out[0] = (float)(chamfer + vq + tyy + tcr + el);
    }
}

// ---------------------------------------------------------------- launch
extern "C" void kernel_launch(void* const* d_in, const int* in_sizes, int n_in,
                              void* d_out, int out_size, void* d_ws, size_t ws_size,
                              hipStream_t stream) {
    const float* x   = (const float*)d_in[0];
    const float* y   = (const float*)d_in[1];
    const float* enc = (const float*)d_in[2];
    const float* pc  = (const float*)d_in[3];
    const float* sf  = (const float*)d_in[4];
    const float* pf  = (const float*)d_in[5];
    const float* Ts  = (const float*)d_in[6];
    const float* Tc  = (const float*)d_in[7];
    const float* emb = (const float*)d_in[8];
    float* out = (float*)d_out;

    char* ws = (char*)d_ws;
    unsigned* rowmin         = (unsigned*)(ws + 0);        // 32 KB
    unsigned* colmin         = (unsigned*)(ws + 32768);    // 32 KB
    float* lq                = (float*)(ws + 65536);       // 32 KB
    float* pq                = (float*)(ws + 98304);       // 64 KB
    unsigned long long* vqbP = (unsigned long long*)(ws + 163840); // 256 KB (4x8192 u64)
    double* pT               = (double*)(ws + 425984);     // 16 KB
    double* pE               = (double*)(ws + 442368);
    double* pV               = (double*)(ws + 458752);
    double* pvq              = (double*)(ws + 475136);     // 2 KB
    double* pyy              = (double*)(ws + 477184);     // 8 KB

    hipLaunchKernelGGL(k_vq, dim3(320), dim3(512), 0, stream,
                       enc, emb, sf, pf, lq, pq, rowmin, colmin, vqbP);
    hipLaunchKernelGGL(k_mega, dim3(4352), dim3(256), 0, stream,
                       x, y, pc, enc, emb, Ts, Tc, lq, pq, vqbP,
                       rowmin, colmin, pT, pE, pV, pyy, pvq);
    hipLaunchKernelGGL(k_final, dim3(1), dim3(1024), 0, stream, rowmin, colmin,
                       pT, pE, pV, pyy, pvq, out);
}

// Round 10
// 169.228 us; speedup vs baseline: 3.7249x; 1.0142x over previous
//
#include <hip/hip_runtime.h>

#define B_ 4
#define N_ 2048
#define M_ 2048
#define M2_ 4096
#define D_ 128
#define K_ 512

__constant__ float LIGQ[10]  = {0.f,-0.3f,-0.4f,-0.1f,0.1f,-0.2f,-0.1f,-0.1f,-0.1f,0.1f};
__constant__ float PROTQ[4]  = {0.f,-0.3f,-0.4f,-0.2f};

// ---------------------------------------------------------------- VQ argmin GEMM + absorbed setup
// blocks 0..255: 128x128 tile scoring, 256 thr = 16(ti)x16(tj), 8x8 acc
// blocks 256..287: lq; 288..351: pq; 352..383: rowmin/colmin init
__global__ __launch_bounds__(256) void k_vq(const float* __restrict__ enc,
                                            const float* __restrict__ emb,
                                            const float* __restrict__ sf,
                                            const float* __restrict__ pf,
                                            float* lq, float* pq,
                                            unsigned* rowmin, unsigned* colmin,
                                            unsigned long long* vqbPart) {
    __shared__ __align__(16) float lf[128 * 64];
    __shared__ __align__(16) float le[128 * 64];
    __shared__ float e2s[128];
    int bid = blockIdx.x;
    int tid = threadIdx.x;

    if (bid >= 256) {
        int sb = bid - 256;
        if (sb < 32) {                      // lq: 256 rows/block
            int j = sb * 256 + tid;
            const float* f = sf + (size_t)j * D_;
            float4 v0 = *(const float4*)f;
            float4 v1 = *(const float4*)(f + 4);
            float2 v2 = *(const float2*)(f + 8);
            float best = v0.x; int bi = 0;
            if (v0.y > best) { best = v0.y; bi = 1; }
            if (v0.z > best) { best = v0.z; bi = 2; }
            if (v0.w > best) { best = v0.w; bi = 3; }
            if (v1.x > best) { best = v1.x; bi = 4; }
            if (v1.y > best) { best = v1.y; bi = 5; }
            if (v1.z > best) { best = v1.z; bi = 6; }
            if (v1.w > best) { best = v1.w; bi = 7; }
            if (v2.x > best) { best = v2.x; bi = 8; }
            if (v2.y > best) { best = v2.y; bi = 9; }
            lq[j] = LIGQ[bi];
        } else if (sb < 96) {               // pq: 256 rows/block
            int p = (sb - 32) * 256 + tid;
            float4 v0 = *(const float4*)(pf + (size_t)p * D_);
            float best = v0.x; int bi = 0;
            if (v0.y > best) { best = v0.y; bi = 1; }
            if (v0.z > best) { best = v0.z; bi = 2; }
            if (v0.w > best) { best = v0.w; bi = 3; }
            pq[p] = PROTQ[bi];
        } else {                            // init chamfer mins
            int i = (sb - 96) * 256 + tid;
            rowmin[i] = 0x7F800000u;
            colmin[i] = 0x7F800000u;
        }
        return;
    }

    int rt = bid >> 2, ct = bid & 3;
    int r0 = rt * 128, c0 = ct * 128;
    int tj = tid & 15, ti = tid >> 4;

    // per-block e2 for this block's 128 codes (emb is L2-hot, 256 KB total)
    float e2r = 0.f;
    if (tid < 128) {
        const float* e = emb + (size_t)(c0 + tid) * D_;
        float s0 = 0.f, s1 = 0.f, s2 = 0.f, s3 = 0.f;
        for (int d = 0; d < D_; d += 4) {
            float4 v = *(const float4*)&e[d];
            s0 = fmaf(v.x, v.x, s0);
            s1 = fmaf(v.y, v.y, s1);
            s2 = fmaf(v.z, v.z, s2);
            s3 = fmaf(v.w, v.w, s3);
        }
        e2r = (s0 + s1) + (s2 + s3);
    }

    float acc[8][8];
#pragma unroll
    for (int a = 0; a < 8; a++)
#pragma unroll
        for (int b = 0; b < 8; b++) acc[a][b] = 0.f;

    for (int kc = 0; kc < 2; kc++) {
        for (int v = tid; v < 128 * 16; v += 256) {
            int r  = v >> 4;
            int d4 = (v & 15) << 2;
            int dsw = d4 ^ (((r >> 3) & 7) << 2);
            *(float4*)&lf[r * 64 + dsw] = *(const float4*)&enc[((size_t)(r0 + r)) * D_ + kc * 64 + d4];
            *(float4*)&le[r * 64 + dsw] = *(const float4*)&emb[((size_t)(c0 + r)) * D_ + kc * 64 + d4];
        }
        __syncthreads();
        int fgrp = (ti & 7) << 2;
        int egrp = (tj & 7) << 2;
#pragma unroll 4
        for (int d4 = 0; d4 < 64; d4 += 4) {
            float4 fa[8], eb[8];
            int fsw = d4 ^ fgrp;
            int esw = d4 ^ egrp;
#pragma unroll
            for (int rr = 0; rr < 8; rr++) fa[rr] = *(float4*)&lf[(ti * 8 + rr) * 64 + fsw];
#pragma unroll
            for (int cc = 0; cc < 8; cc++) eb[cc] = *(float4*)&le[(tj * 8 + cc) * 64 + esw];
#pragma unroll
            for (int rr = 0; rr < 8; rr++)
#pragma unroll
                for (int cc = 0; cc < 8; cc++) {
                    acc[rr][cc] = fmaf(fa[rr].x, eb[cc].x, acc[rr][cc]);
                    acc[rr][cc] = fmaf(fa[rr].y, eb[cc].y, acc[rr][cc]);
                    acc[rr][cc] = fmaf(fa[rr].z, eb[cc].z, acc[rr][cc]);
                    acc[rr][cc] = fmaf(fa[rr].w, eb[cc].w, acc[rr][cc]);
                }
        }
        __syncthreads();
    }

    if (tid < 128) e2s[tid] = e2r;
    __syncthreads();

    // per-row best over this block's 128 codes; pack (orderable score | idx)
    unsigned long long* red = (unsigned long long*)lf;    // 17.4 KB
#pragma unroll
    for (int rr = 0; rr < 8; rr++) {
        int r = ti * 8 + rr;
        float bs = __uint_as_float(0x7F800000u); int bidx = 0;
#pragma unroll
        for (int cc = 0; cc < 8; cc++) {
            int c = tj * 8 + cc;
            float s = e2s[c] - 2.f * acc[rr][cc];
            if (s < bs) { bs = s; bidx = c0 + c; }
        }
        unsigned ub = __float_as_uint(bs);
        ub = (ub & 0x80000000u) ? ~ub : (ub | 0x80000000u);
        red[r * 17 + tj] = ((unsigned long long)ub << 32) | (unsigned)bidx;
    }
    __syncthreads();
    if (tid < 128) {
        unsigned long long mn = red[tid * 17 + 0];
        for (int t = 1; t < 16; t++) {
            unsigned long long v = red[tid * 17 + t];
            mn = (v < mn) ? v : mn;
        }
        vqbPart[ct * 8192 + r0 + tid] = mn;   // plain store, no atomics
    }
}

// ---------------------------------------------------------------- mega: cross | yy | chamfer | vqep
__global__ __launch_bounds__(256) void k_mega(const float* __restrict__ x,
                                              const float* __restrict__ yg,
                                              const float* __restrict__ pg,
                                              const float* __restrict__ enc,
                                              const float* __restrict__ emb,
                                              const float* __restrict__ Ts,
                                              const float* __restrict__ Tc,
                                              const float* __restrict__ lq,
                                              const float* __restrict__ pq,
                                              const unsigned long long* __restrict__ vqbPart,
                                              unsigned* rowmin, unsigned* colmin,
                                              double* pT, double* pE, double* pV,
                                              double* pyy, double* pvq) {
    __shared__ __align__(16) char smem[8448];
    int vb = blockIdx.x;                    // direct mapping (permutation regressed: R9)
    int tid = threadIdx.x;

    if (vb < 2048) {
        // ------------------ cross: tpl_cross + elec + vdw
        float4* lyq = (float4*)smem;
        float4* lpq = (float4*)(smem + 4096);
        double* wred = (double*)(smem + 8192);
        int it = vb >> 6, jt = vb & 63;
        int i0 = it * 64, j0 = jt * 64;
        {
            int b = tid >> 6, r = tid & 63;
            const float* yp = &yg[((size_t)(b * M_ + i0 + r)) * 3];
            lyq[tid] = make_float4(yp[0], yp[1], yp[2], lq[b * M_ + i0 + r]);
            const float* pp = &pg[((size_t)(b * M2_ + j0 + r)) * 3];
            lpq[tid] = make_float4(pp[0], pp[1], pp[2], pq[b * M2_ + j0 + r]);
        }
        __syncthreads();

        int tj = tid & 15, ti = tid >> 4;
        float tcs[4][4];
#pragma unroll
        for (int a = 0; a < 4; a++) {
            const float* tr = &Tc[((size_t)(i0 + ti * 4 + a)) * M2_ + j0 + tj];
#pragma unroll
            for (int jj = 0; jj < 4; jj++) tcs[a][jj] = tr[jj * 16];
        }

        float s_tpl = 0.f, s_elec = 0.f, s_vdw = 0.f;
#pragma unroll
        for (int b = 0; b < B_; b++) {
            float4 row[4], col[4];
#pragma unroll
            for (int a = 0; a < 4; a++) row[a] = lyq[b * 64 + ti * 4 + a];
#pragma unroll
            for (int jj = 0; jj < 4; jj++) col[jj] = lpq[b * 64 + jj * 16 + tj];
#pragma unroll
            for (int jj = 0; jj < 4; jj++)
#pragma unroll
                for (int a = 0; a < 4; a++) {
                    float dx = row[a].x - col[jj].x;
                    float dy = row[a].y - col[jj].y;
                    float dz = row[a].z - col[jj].z;
                    float d2 = fmaf(dz, dz, fmaf(dy, dy, dx * dx));
                    float r  = __builtin_amdgcn_sqrtf(d2);
                    float s  = r - tcs[a][jj];
                    s_tpl = fmaf(s, s, s_tpl);
                    float dd  = r + 0.01f;
                    float inv = __builtin_amdgcn_rcpf(dd);
                    float i2 = inv * inv;
                    float i6 = i2 * i2 * i2;
                    s_vdw = fmaf(i6, i6 - 1.f, s_vdw);
                    s_elec = fmaf(row[a].w * col[jj].w, inv, s_elec);
                }
        }
        double dt = (double)s_tpl, de = (double)s_elec, dv = (double)s_vdw;
        for (int off = 32; off; off >>= 1) {
            dt += __shfl_down(dt, off);
            de += __shfl_down(de, off);
            dv += __shfl_down(dv, off);
        }
        int wv = tid >> 6;
        if ((tid & 63) == 0) { wred[wv] = dt; wred[4 + wv] = de; wred[8 + wv] = dv; }
        __syncthreads();
        if (tid == 0) {
            pT[vb] = (wred[0] + wred[1]) + (wred[2] + wred[3]);
            pE[vb] = (wred[4] + wred[5]) + (wred[6] + wred[7]);
            pV[vb] = (wred[8] + wred[9]) + (wred[10] + wred[11]);
        }
    } else if (vb < 3072) {
        // ------------------ yy: tpl_scaffold
        int sb = vb - 2048;
        float4* la4 = (float4*)smem;
        float4* lb4 = (float4*)(smem + 4096);
        double* wred = (double*)(smem + 8192);
        int it = sb >> 5, jt = sb & 31;
        int i0 = it * 64, j0 = jt * 64;
        {
            int b = tid >> 6, r = tid & 63;
            const float* ap = &yg[((size_t)(b * M_ + i0 + r)) * 3];
            la4[tid] = make_float4(ap[0], ap[1], ap[2], 0.f);
            const float* bp = &yg[((size_t)(b * M_ + j0 + r)) * 3];
            lb4[tid] = make_float4(bp[0], bp[1], bp[2], 0.f);
        }
        __syncthreads();

        int tj = tid & 15, ti = tid >> 4;
        float tcs[4][4];
#pragma unroll
        for (int a = 0; a < 4; a++) {
            const float* tr = &Ts[((size_t)(i0 + ti * 4 + a)) * M_ + j0 + tj];
#pragma unroll
            for (int jj = 0; jj < 4; jj++) tcs[a][jj] = tr[jj * 16];
        }
        float s_tpl = 0.f;
#pragma unroll
        for (int b = 0; b < B_; b++) {
            float4 row[4], col[4];
#pragma unroll
            for (int a = 0; a < 4; a++) row[a] = la4[b * 64 + ti * 4 + a];
#pragma unroll
            for (int jj = 0; jj < 4; jj++) col[jj] = lb4[b * 64 + jj * 16 + tj];
#pragma unroll
            for (int jj = 0; jj < 4; jj++)
#pragma unroll
                for (int a = 0; a < 4; a++) {
                    float dx = row[a].x - col[jj].x;
                    float dy = row[a].y - col[jj].y;
                    float dz = row[a].z - col[jj].z;
                    float d2 = fmaf(dz, dz, fmaf(dy, dy, dx * dx));
                    float r  = __builtin_amdgcn_sqrtf(d2);
                    float s  = r - tcs[a][jj];
                    s_tpl = fmaf(s, s, s_tpl);
                }
        }
        double dt = (double)s_tpl;
        for (int off = 32; off; off >>= 1) dt += __shfl_down(dt, off);
        if ((tid & 63) == 0) wred[tid >> 6] = dt;
        __syncthreads();
        if (tid == 0) pyy[sb] = (wred[0] + wred[1]) + (wred[2] + wred[3]);
    } else if (vb < 4096) {
        // ------------------ chamfer (both sides)
        int sub = vb - 3072;
        const float* A; const float* Bsd; unsigned* outmin;
        if (sub < 512) { A = x;  Bsd = yg; outmin = rowmin; }
        else           { A = yg; Bsd = x;  outmin = colmin; sub -= 512; }
        float4* lb = (float4*)smem;
        int rc = sub >> 4;
        int jc = sub & 15;
        int row = rc * 256 + tid;
        int b = row >> 11;
        int j0 = jc * 128;

        for (int t = tid; t < 128 * 3; t += 256) {
            int j = t / 3, c = t % 3;
            ((float*)&lb[j])[c] = Bsd[((size_t)(b * 2048 + j0 + j)) * 3 + c];
        }
        __syncthreads();

        const float* p = &A[(size_t)row * 3];
        float ax = p[0], ay = p[1], az = p[2];
        float m2 = __uint_as_float(0x7F800000u);
#pragma unroll 4
        for (int j = 0; j < 128; j++) {
            float4 pv = lb[j];
            float dx = ax - pv.x, dy = ay - pv.y, dz = az - pv.z;
            m2 = fminf(m2, fmaf(dz, dz, fmaf(dy, dy, dx * dx)));
        }
        atomicMin(&outmin[row], __float_as_uint(m2));
    } else {
        // ------------------ vqep: VQ MSE, 32 rows per block; argmin = min of 4 partials
        double* sred = (double*)smem;
        int base = (vb - 4096) * 32;
        int wv = tid >> 6, lane = tid & 63;
        double s = 0.0;
#pragma unroll
        for (int it = 0; it < 8; it++) {
            int w = base + wv * 8 + it;
            unsigned long long m0 = vqbPart[w];
            unsigned long long m1 = vqbPart[8192 + w];
            unsigned long long m2_ = vqbPart[16384 + w];
            unsigned long long m3 = vqbPart[24576 + w];
            m0 = (m1 < m0) ? m1 : m0;
            m2_ = (m3 < m2_) ? m3 : m2_;
            m0 = (m2_ < m0) ? m2_ : m0;
            int idx = (int)(m0 & 0xFFFFFFFFu);
            float2 fv = *(const float2*)&enc[(size_t)w * D_ + lane * 2];
            float2 ev = *(const float2*)&emb[(size_t)idx * D_ + lane * 2];
            float d0 = ev.x - fv.x, d1 = ev.y - fv.y;
            s += (double)(d0 * d0) + (double)(d1 * d1);
        }
        for (int off = 32; off; off >>= 1) s += __shfl_down(s, off);
        if (lane == 0) sred[wv] = s;
        __syncthreads();
        if (tid == 0) pvq[vb - 4096] = (sred[0] + sred[1]) + (sred[2] + sred[3]);
    }
}

// ---------------------------------------------------------------- final combine (vectorized reads)
__global__ __launch_bounds__(1024) void k_final(const unsigned* __restrict__ rowmin,
                                                const unsigned* __restrict__ colmin,
                                                const double* __restrict__ pT,
                                                const double* __restrict__ pE,
                                                const double* __restrict__ pV,
                                                const double* __restrict__ pyy,
                                                const double* __restrict__ pvq,
                                                float* out) {
    __shared__ double sh[6][1024];
    int tid = threadIdx.x;
    double sc = 0.0, sT = 0.0, sE = 0.0, sV = 0.0, sY = 0.0, sQ = 0.0;
    for (int i = tid; i < 2048; i += 1024) {
        uint4 v = ((const uint4*)rowmin)[i];
        sc += (double)__builtin_amdgcn_sqrtf(__uint_as_float(v.x))
            + (double)__builtin_amdgcn_sqrtf(__uint_as_float(v.y))
            + (double)__builtin_amdgcn_sqrtf(__uint_as_float(v.z))
            + (double)__builtin_amdgcn_sqrtf(__uint_as_float(v.w));
        uint4 w = ((const uint4*)colmin)[i];
        sc += (double)__builtin_amdgcn_sqrtf(__uint_as_float(w.x))
            + (double)__builtin_amdgcn_sqrtf(__uint_as_float(w.y))
            + (double)__builtin_amdgcn_sqrtf(__uint_as_float(w.z))
            + (double)__builtin_amdgcn_sqrtf(__uint_as_float(w.w));
    }
    {
        double2 a = ((const double2*)pT)[tid];  sT += a.x + a.y;
        double2 b = ((const double2*)pE)[tid];  sE += b.x + b.y;
        double2 c = ((const double2*)pV)[tid];  sV += c.x + c.y;
        sY += pyy[tid];
        if (tid < 256) sQ = pvq[tid];
    }
    sh[0][tid] = sc; sh[1][tid] = sT; sh[2][tid] = sE;
    sh[3][tid] = sV; sh[4][tid] = sY; sh[5][tid] = sQ;
    __syncthreads();
    for (int st = 512; st; st >>= 1) {
        if (tid < st)
#pragma unroll
            for (int q = 0; q < 6; q++) sh[q][tid] += sh[q][tid + st];
        __syncthreads();
    }
    if (tid == 0) {
        double chamfer = sh[0][0] / (double)(B_ * N_);
        double vq  = 1.25 * sh[5][0] / (double)((size_t)B_ * M_ * D_);
        double tyy = sh[4][0] / (double)((size_t)B_ * M_ * M_);
        double tcr = sh[1][0] / (double)((size_t)B_ * M_ * M2_);
        double el  = 0.1 * (sh[2][0] + sh[3][0]) / (double)B_;
        out[0] = (float)(chamfer + vq + tyy + tcr + el);
    }
}

// ---------------------------------------------------------------- launch
extern "C" void kernel_launch(void* const* d_in, const int* in_sizes, int n_in,
                              void* d_out, int out_size, void* d_ws, size_t ws_size,
                              hipStream_t stream) {
    const float* x   = (const float*)d_in[0];
    const float* y   = (const float*)d_in[1];
    const float* enc = (const float*)d_in[2];
    const float* pc  = (const float*)d_in[3];
    const float* sf  = (const float*)d_in[4];
    const float* pf  = (const float*)d_in[5];
    const float* Ts  = (const float*)d_in[6];
    const float* Tc  = (const float*)d_in[7];
    const float* emb = (const float*)d_in[8];
    float* out = (float*)d_out;

    char* ws = (char*)d_ws;
    unsigned* rowmin         = (unsigned*)(ws + 0);        // 32 KB
    unsigned* colmin         = (unsigned*)(ws + 32768);    // 32 KB
    float* lq                = (float*)(ws + 65536);       // 32 KB
    float* pq                = (float*)(ws + 98304);       // 64 KB
    unsigned long long* vqbP = (unsigned long long*)(ws + 163840); // 256 KB
    double* pT               = (double*)(ws + 425984);     // 16 KB
    double* pE               = (double*)(ws + 442368);
    double* pV               = (double*)(ws + 458752);
    double* pvq              = (double*)(ws + 475136);     // 2 KB
    double* pyy              = (double*)(ws + 477184);     // 8 KB

    hipLaunchKernelGGL(k_vq, dim3(384), dim3(256), 0, stream,
                       enc, emb, sf, pf, lq, pq, rowmin, colmin, vqbP);
    hipLaunchKernelGGL(k_mega, dim3(4352), dim3(256), 0, stream,
                       x, y, pc, enc, emb, Ts, Tc, lq, pq, vqbP,
                       rowmin, colmin, pT, pE, pV, pyy, pvq);
    hipLaunchKernelGGL(k_final, dim3(1), dim3(1024), 0, stream, rowmin, colmin,
                       pT, pE, pV, pyy, pvq, out);
}